// Round 9
// baseline (856.466 us; speedup 1.0000x reference)
//
#include <hip/hip_runtime.h>
#include <math.h>

#define DD 1024
#define MM 8192   // B*S rows
#define SS 128
#define DINN 64
#define DOUTN 64

typedef _Float16 f16;
typedef _Float16 f16x8 __attribute__((ext_vector_type(8)));
typedef _Float16 f16x4 __attribute__((ext_vector_type(4)));
typedef float    f32x4 __attribute__((ext_vector_type(4)));

// direct global->LDS, 16B per lane; LDS base must be wave-uniform
#define GLOAD_LDS(g, l) \
  __builtin_amdgcn_global_load_lds((const __attribute__((address_space(1))) void*)(g), \
                                   (__attribute__((address_space(3))) void*)(l), 16, 0, 0)

// split helpers: store hi' = f16(y)*64, lo' = f16((y - hi)*64); y = hi'/64 + lo'/4096.
__device__ __forceinline__ void split_store(float y, f16* __restrict__ hp, f16* __restrict__ lp, size_t idx) {
  f16 h = (f16)y;
  hp[idx] = h * (f16)64.0f;
  lp[idx] = (f16)((y - (float)h) * 64.0f);
}
__device__ __forceinline__ float join_load(const f16* __restrict__ hp, const f16* __restrict__ lp, size_t idx) {
  return (float)hp[idx] * 0.015625f + (float)lp[idx] * 0.000244140625f;
}

// ---------------------------------------------------------------------------
// Split-f16 MFMA GEMM.  Y = (Ahi+Alo/64)(Bhi+Blo/64)/4096, terms HH+HL+LH.
// A planes [M][K] (lda), B planes [N][K] (ldb), C planes [M][ldc].
// 2-wave (128-thread) blocks; BN=128; BK=32.
//   MSPLIT=1: block 128x128, waves split m -> wave-tile 64x128 (MT=4,NT=8),
//             96 MFMA / 24 ds_read_b128 = ratio 4.0  (full GEMMs).
//   MSPLIT=0: block  64x128, waves split n -> wave-tile 64x64  (MT=4,NT=4),
//             48 MFMA / 16 reads = ratio 3.0          (half GEMMs, W12).
// LDS per-plane tiles [rows][32] f16; 16B-chunk XOR swizzle s(row)=(row>>1)&3
// (conflict-free b128 frag reads; verified R7: SQ_LDS_BANK_CONFLICT = 0).
// SHIFT: store col = (n + SHIFT*(m>>6)) & 1023 (scalar path only).
// EPI:  y = y_old + tanh(acc/4096).
// ---------------------------------------------------------------------------
template<int MT, int NT, bool MSPLIT, bool EPI, int SHIFT>
__global__ __launch_bounds__(128)
void k_gemm16(const f16* __restrict__ Ahi, const f16* __restrict__ Alo, int lda,
              const f16* __restrict__ Bhi, const f16* __restrict__ Blo, int ldb,
              f16* __restrict__ Chi, f16* __restrict__ Clo, int ldc, int K) {
  constexpr int BM = MSPLIT ? 128 : 64;
  constexpr int AI = BM / 32;          // A staging calls (128 chunks/call)
  __shared__ f16 sA[2][2][BM * 32];
  __shared__ f16 sB[2][2][128 * 32];

  // XCD-aware swizzle (nwg % 8 == 0 for all our grids)
  const int nwg = gridDim.x * gridDim.y;
  int wg = blockIdx.y * gridDim.x + blockIdx.x;
  wg = (wg & 7) * (nwg >> 3) + (wg >> 3);
  const int bx = wg % gridDim.x, by = wg / gridDim.x;

  const int col0 = bx * 128, row0 = by * BM;
  const int u = threadIdx.x, lane = u & 63, wv = u >> 6;   // wv in {0,1}
  const int mh = MSPLIT ? wv * 64 : 0;
  const int nh = MSPLIT ? 0 : wv * 64;

  unsigned aoff[AI], boff[4];
  unsigned dstA[AI], dstB[4];
#pragma unroll
  for (int i = 0; i < AI; ++i) {
    const int P = i * 128 + u;
    const int row = P >> 2, kc = (P & 3) ^ ((row >> 1) & 3);
    aoff[i] = (unsigned)(row0 + row) * lda + kc * 8;
    dstA[i] = (i * 128 + wv * 64) * 8;
  }
#pragma unroll
  for (int i = 0; i < 4; ++i) {
    const int P = i * 128 + u;
    const int row = P >> 2, kc = (P & 3) ^ ((row >> 1) & 3);
    boff[i] = (unsigned)(col0 + row) * ldb + kc * 8;
    dstB[i] = (i * 128 + wv * 64) * 8;
  }

  // conflict-free frag chunk: (lane>>4) ^ s(row), s = (row>>1)&3, row=(lane&15)
  const int frag = (lane & 15) * 32 + (((lane >> 4) ^ ((lane >> 1) & 3)) * 8);

  f32x4 acc[MT][NT];
#pragma unroll
  for (int i = 0; i < MT; ++i)
#pragma unroll
    for (int j = 0; j < NT; ++j) acc[i][j] = (f32x4){0.f, 0.f, 0.f, 0.f};

  auto stage = [&](int b, int k0) {
#pragma unroll
    for (int i = 0; i < AI; ++i) {
      GLOAD_LDS(Ahi + aoff[i] + k0, &sA[b][0][dstA[i]]);
      GLOAD_LDS(Alo + aoff[i] + k0, &sA[b][1][dstA[i]]);
    }
#pragma unroll
    for (int i = 0; i < 4; ++i) {
      GLOAD_LDS(Bhi + boff[i] + k0, &sB[b][0][dstB[i]]);
      GLOAD_LDS(Blo + boff[i] + k0, &sB[b][1][dstB[i]]);
    }
  };

  const int niter = K >> 5;
  stage(0, 0);
  __syncthreads();

  int buf = 0;
  for (int it = 0; it < niter; ++it) {
    if (it + 1 < niter) stage(buf ^ 1, (it + 1) << 5);
    f16x8 aH[MT], aL[MT];
#pragma unroll
    for (int mt = 0; mt < MT; ++mt) {
      aH[mt] = *(const f16x8*)&sA[buf][0][(mh + mt * 16) * 32 + frag];
      aL[mt] = *(const f16x8*)&sA[buf][1][(mh + mt * 16) * 32 + frag];
    }
#pragma unroll
    for (int nt = 0; nt < NT; ++nt) {
      const f16x8 bH = *(const f16x8*)&sB[buf][0][(nh + nt * 16) * 32 + frag];
      const f16x8 bL = *(const f16x8*)&sB[buf][1][(nh + nt * 16) * 32 + frag];
#pragma unroll
      for (int mt = 0; mt < MT; ++mt) {
        acc[mt][nt] = __builtin_amdgcn_mfma_f32_16x16x32_f16(aH[mt], bH, acc[mt][nt], 0, 0, 0);
        acc[mt][nt] = __builtin_amdgcn_mfma_f32_16x16x32_f16(aH[mt], bL, acc[mt][nt], 0, 0, 0);
        acc[mt][nt] = __builtin_amdgcn_mfma_f32_16x16x32_f16(aL[mt], bH, acc[mt][nt], 0, 0, 0);
      }
    }
    __syncthreads();
    buf ^= 1;
  }

  if constexpr (SHIFT == 0) {
    // ---- vectorized epilogue: per-wave LDS transpose staging (reuse sB) ----
    constexpr int NSPAN = NT * 16;          // per-wave n-span
    constexpr int STR = NSPAN + 4;          // f16 row stride
    constexpr int CPR = NSPAN / 8;          // 16B chunks per row
    f16* eH = ((f16*)sB) + wv * (16 * STR * 2);
    f16* eL = eH + 16 * STR;
    const int lrow4 = (lane >> 4) << 2;
    const int lcol = lane & 15;
#pragma unroll
    for (int mt = 0; mt < MT; ++mt) {
#pragma unroll
      for (int nt = 0; nt < NT; ++nt) {
        const f32x4 a = acc[mt][nt];
#pragma unroll
        for (int r = 0; r < 4; ++r) {
          const float y = a[r] * 0.000244140625f;
          const f16 h = (f16)y;
          const int o = (lrow4 + r) * STR + nt * 16 + lcol;
          eH[o] = h * (f16)64.0f;
          eL[o] = (f16)((y - (float)h) * 64.0f);
        }
      }
#pragma unroll
      for (int j = 0; j < (16 * CPR) / 64; ++j) {
        const int idx = j * 64 + lane;
        const int row = idx / CPR, ch = idx % CPR;
        const f16x8 vh = *(const f16x8*)&eH[row * STR + ch * 8];
        const f16x8 vl = *(const f16x8*)&eL[row * STR + ch * 8];
        const int m = row0 + mh + mt * 16 + row;
        const size_t gi = (size_t)m * ldc + col0 + nh + ch * 8;
        if (EPI) {
          const f16x8 oh = *(const f16x8*)&Chi[gi];
          const f16x8 ol = *(const f16x8*)&Clo[gi];
          f16x8 rh, rl;
#pragma unroll
          for (int q = 0; q < 8; ++q) {
            const float yn = (float)vh[q] * 0.015625f + (float)vl[q] * 0.000244140625f;
            const float y  = (float)oh[q] * 0.015625f + (float)ol[q] * 0.000244140625f + tanhf(yn);
            const f16 h = (f16)y;
            rh[q] = h * (f16)64.0f;
            rl[q] = (f16)((y - (float)h) * 64.0f);
          }
          *(f16x8*)&Chi[gi] = rh;
          *(f16x8*)&Clo[gi] = rl;
        } else {
          *(f16x8*)&Chi[gi] = vh;
          *(f16x8*)&Clo[gi] = vl;
        }
      }
    }
  } else {
    // ---- scalar epilogue (rotor shift folded into col index) ----
#pragma unroll
    for (int mt = 0; mt < MT; ++mt)
#pragma unroll
      for (int nt = 0; nt < NT; ++nt) {
        const f32x4 a = acc[mt][nt];
        const int n_base = col0 + nh + nt * 16 + (lane & 15);
#pragma unroll
        for (int r = 0; r < 4; ++r) {
          const int m = row0 + mh + mt * 16 + ((lane >> 4) << 2) + r;
          int n = (n_base + SHIFT * (m >> 6) + 2048) & (DD - 1);
          const size_t idx = (size_t)m * ldc + n;
          float y = a[r] * 0.000244140625f;
          if (EPI) y = join_load(Chi, Clo, idx) + tanhf(y);
          split_store(y, Chi, Clo, idx);
        }
      }
  }
}

// ---------------------------------------------------------------------------
// input projection as MFMA GEMM:
//   h0_pre[r][j] = sum_k x[b][t][k]*A2[(j+t)&1023][k] + cvec[(j+t)&1023]
//   (r = t*64+b; t = blockIdx.y uniform since BM=64)
// ---------------------------------------------------------------------------
__global__ __launch_bounds__(256)
void k_in_mfma(const f16* __restrict__ xH, const f16* __restrict__ xL,
               const f16* __restrict__ A2H, const f16* __restrict__ A2L,
               const float* __restrict__ cvec,
               f16* __restrict__ hH, f16* __restrict__ hL) {
  __shared__ f16 sA[2][2][64 * 32];
  __shared__ f16 sB[2][2][128 * 32];
  const int bx = blockIdx.x, by = blockIdx.y;   // n-block, m-block(=t)
  const int col0 = bx * 128, row0 = by * 64, t = by;
  const int u = threadIdx.x, lane = u & 63, wv = u >> 6;
  const int mh = (wv >> 1) * 32;
  const int nh = (wv & 1) * 64;

  unsigned aoff, boff[2], dstA, dstB[2];
  {
    const int row = u >> 2, kc = (u & 3) ^ ((row >> 1) & 3);
    aoff = (unsigned)(row * SS + t) * DINN + kc * 8;
    dstA = (unsigned)(wv * 64) * 8;
  }
#pragma unroll
  for (int i = 0; i < 2; ++i) {
    const int P = i * 256 + u;
    const int row = P >> 2, kc = (P & 3) ^ ((row >> 1) & 3);
    const int src = (col0 + row + t) & (DD - 1);
    boff[i] = (unsigned)src * DINN + kc * 8;
    dstB[i] = (i * 256 + wv * 64) * 8;
  }

  const int frag = (lane & 15) * 32 + (((lane >> 4) ^ ((lane >> 1) & 3)) * 8);

  f32x4 acc[2][4];
#pragma unroll
  for (int i = 0; i < 2; ++i)
#pragma unroll
    for (int j = 0; j < 4; ++j) acc[i][j] = (f32x4){0.f, 0.f, 0.f, 0.f};

  auto stage = [&](int b, int k0) {
    GLOAD_LDS(xH + aoff + k0, &sA[b][0][dstA]);
    GLOAD_LDS(xL + aoff + k0, &sA[b][1][dstA]);
#pragma unroll
    for (int i = 0; i < 2; ++i) {
      GLOAD_LDS(A2H + boff[i] + k0, &sB[b][0][dstB[i]]);
      GLOAD_LDS(A2L + boff[i] + k0, &sB[b][1][dstB[i]]);
    }
  };

  stage(0, 0);
  __syncthreads();
  int buf = 0;
#pragma unroll
  for (int it = 0; it < 2; ++it) {
    if (it == 0) stage(1, 32);
    f16x8 aH[2], aL[2], bH[4], bL[4];
#pragma unroll
    for (int mt = 0; mt < 2; ++mt) {
      aH[mt] = *(const f16x8*)&sA[buf][0][(mh + mt * 16) * 32 + frag];
      aL[mt] = *(const f16x8*)&sA[buf][1][(mh + mt * 16) * 32 + frag];
    }
#pragma unroll
    for (int nt = 0; nt < 4; ++nt) {
      bH[nt] = *(const f16x8*)&sB[buf][0][(nh + nt * 16) * 32 + frag];
      bL[nt] = *(const f16x8*)&sB[buf][1][(nh + nt * 16) * 32 + frag];
    }
#pragma unroll
    for (int mt = 0; mt < 2; ++mt)
#pragma unroll
      for (int nt = 0; nt < 4; ++nt) {
        acc[mt][nt] = __builtin_amdgcn_mfma_f32_16x16x32_f16(aH[mt], bH[nt], acc[mt][nt], 0, 0, 0);
        acc[mt][nt] = __builtin_amdgcn_mfma_f32_16x16x32_f16(aH[mt], bL[nt], acc[mt][nt], 0, 0, 0);
        acc[mt][nt] = __builtin_amdgcn_mfma_f32_16x16x32_f16(aL[mt], bH[nt], acc[mt][nt], 0, 0, 0);
      }
    __syncthreads();
    buf ^= 1;
  }

  f16* eH = ((f16*)sB) + wv * (16 * 84 * 2);
  f16* eL = eH + 16 * 84;
  const int lrow4 = (lane >> 4) << 2;
  const int lcol = lane & 15;
#pragma unroll
  for (int mt = 0; mt < 2; ++mt) {
#pragma unroll
    for (int nt = 0; nt < 4; ++nt) {
      const f32x4 a = acc[mt][nt];
      const int n = col0 + nh + nt * 16 + lcol;
      const float cv = cvec[(n + t) & (DD - 1)];
#pragma unroll
      for (int r = 0; r < 4; ++r) {
        const float y = a[r] * 0.000244140625f + cv;
        const f16 h = (f16)y;
        const int o = (lrow4 + r) * 84 + nt * 16 + lcol;
        eH[o] = h * (f16)64.0f;
        eL[o] = (f16)((y - (float)h) * 64.0f);
      }
    }
#pragma unroll
    for (int j = 0; j < 2; ++j) {
      const int idx = j * 64 + lane;
      const int row = idx >> 3, ch = idx & 7;
      const f16x8 vh = *(const f16x8*)&eH[row * 84 + ch * 8];
      const f16x8 vl = *(const f16x8*)&eL[row * 84 + ch * 8];
      const int m = row0 + mh + mt * 16 + row;
      const size_t gi = (size_t)m * DD + col0 + nh + ch * 8;
      *(f16x8*)&hH[gi] = vh;
      *(f16x8*)&hL[gi] = vl;
    }
  }
}

// ---------------------------------------------------------------------------
// output projection as MFMA GEMM: out[b][t][c] = (h @ MoT^T)[r][c] + bo[c]
// ---------------------------------------------------------------------------
__global__ __launch_bounds__(256)
void k_out_mfma(const f16* __restrict__ Ahi, const f16* __restrict__ Alo,
                const f16* __restrict__ Bhi, const f16* __restrict__ Blo,
                const float* __restrict__ bo, float* __restrict__ out) {
  __shared__ f16 sA[2][2][64 * 32];
  __shared__ f16 sB[2][2][64 * 32];
  const int row0 = blockIdx.x * 64;
  const int u = threadIdx.x, lane = u & 63, wv = u >> 6;
  const int mh = (wv >> 1) * 32, nh = (wv & 1) * 32;

  const int srow = u >> 2, skc = (u & 3) ^ ((srow >> 1) & 3);
  const unsigned aoff = (unsigned)(row0 + srow) * DD + skc * 8;
  const unsigned boff = (unsigned)srow * DD + skc * 8;
  const unsigned dst = (unsigned)(wv * 64) * 8;

  const int frag = (lane & 15) * 32 + (((lane >> 4) ^ ((lane >> 1) & 3)) * 8);

  f32x4 acc[2][2];
#pragma unroll
  for (int i = 0; i < 2; ++i)
#pragma unroll
    for (int j = 0; j < 2; ++j) acc[i][j] = (f32x4){0.f, 0.f, 0.f, 0.f};

  auto stage = [&](int b, int k0) {
    GLOAD_LDS(Ahi + aoff + k0, &sA[b][0][dst]);
    GLOAD_LDS(Alo + aoff + k0, &sA[b][1][dst]);
    GLOAD_LDS(Bhi + boff + k0, &sB[b][0][dst]);
    GLOAD_LDS(Blo + boff + k0, &sB[b][1][dst]);
  };

  stage(0, 0);
  __syncthreads();
  int buf = 0;
  for (int it = 0; it < 32; ++it) {
    if (it + 1 < 32) stage(buf ^ 1, (it + 1) << 5);
    f16x8 aH[2], aL[2], bH[2], bL[2];
#pragma unroll
    for (int mt = 0; mt < 2; ++mt) {
      aH[mt] = *(const f16x8*)&sA[buf][0][(mh + mt * 16) * 32 + frag];
      aL[mt] = *(const f16x8*)&sA[buf][1][(mh + mt * 16) * 32 + frag];
    }
#pragma unroll
    for (int nt = 0; nt < 2; ++nt) {
      bH[nt] = *(const f16x8*)&sB[buf][0][(nh + nt * 16) * 32 + frag];
      bL[nt] = *(const f16x8*)&sB[buf][1][(nh + nt * 16) * 32 + frag];
    }
#pragma unroll
    for (int mt = 0; mt < 2; ++mt)
#pragma unroll
      for (int nt = 0; nt < 2; ++nt) {
        acc[mt][nt] = __builtin_amdgcn_mfma_f32_16x16x32_f16(aH[mt], bH[nt], acc[mt][nt], 0, 0, 0);
        acc[mt][nt] = __builtin_amdgcn_mfma_f32_16x16x32_f16(aH[mt], bL[nt], acc[mt][nt], 0, 0, 0);
        acc[mt][nt] = __builtin_amdgcn_mfma_f32_16x16x32_f16(aL[mt], bH[nt], acc[mt][nt], 0, 0, 0);
      }
    __syncthreads();
    buf ^= 1;
  }

#pragma unroll
  for (int mt = 0; mt < 2; ++mt)
#pragma unroll
    for (int nt = 0; nt < 2; ++nt) {
      const f32x4 a = acc[mt][nt];
      const int c = nh + nt * 16 + (lane & 15);
      const float bias = bo[c];
#pragma unroll
      for (int r = 0; r < 4; ++r) {
        const int m = row0 + mh + mt * 16 + ((lane >> 4) << 2) + r;
        const int t = m >> 6, b = m & 63;
        out[((size_t)b * SS + t) * DOUTN + c] = a[r] * 0.000244140625f + bias;
      }
    }
}

// ---------------------------------------------------------------------------
// precompute: splits / transposes
// ---------------------------------------------------------------------------
__global__ __launch_bounds__(256)
void k_split(const float* __restrict__ src, f16* __restrict__ hi, f16* __restrict__ lo) {
  const int i = blockIdx.x * 256 + threadIdx.x;
  const float4 v = ((const float4*)src)[i];
  f16x4 h4, l4;
  const float vv[4] = {v.x, v.y, v.z, v.w};
#pragma unroll
  for (int j = 0; j < 4; ++j) {
    f16 h = (f16)vv[j];
    h4[j] = h * (f16)64.0f;
    l4[j] = (f16)((vv[j] - (float)h) * 64.0f);
  }
  ((f16x4*)hi)[i] = h4;
  ((f16x4*)lo)[i] = l4;
}

// transpose + split: src fp32 [dim][dim] (z-batched) -> planes = src^T
__global__ __launch_bounds__(256)
void k_splitT(const float* __restrict__ src, f16* __restrict__ hi, f16* __restrict__ lo, int dim) {
  const size_t zo = (size_t)blockIdx.z * dim * dim;
  src += zo; hi += zo; lo += zo;
  const int i0 = blockIdx.y * 64, j0 = blockIdx.x * 64;
  __shared__ float tb[64][68];
  const int u = threadIdx.x;
#pragma unroll
  for (int it = 0; it < 4; ++it) {
    const int idx = it * 256 + u, rr = idx >> 4, cc = (idx & 15) * 4;
    *(float4*)&tb[rr][cc] = *(const float4*)&src[(size_t)(i0 + rr) * dim + j0 + cc];
  }
  __syncthreads();
#pragma unroll
  for (int it = 0; it < 4; ++it) {
    const int idx = it * 256 + u, rr = idx >> 4, cc = (idx & 15) * 4;
    f16x4 h4, l4;
#pragma unroll
    for (int j = 0; j < 4; ++j) {
      const float y = tb[cc + j][rr];
      f16 h = (f16)y;
      h4[j] = h * (f16)64.0f;
      l4[j] = (f16)((y - (float)h) * 64.0f);
    }
    const size_t o = (size_t)(j0 + rr) * dim + i0 + cc;
    *(f16x4*)&hi[o] = h4;
    *(f16x4*)&lo[o] = l4;
  }
}

// S = R + R^T, split-stored (symmetric => [n][k] fine)
__global__ __launch_bounds__(256)
void k_symm_split(const float* __restrict__ R, f16* __restrict__ hi, f16* __restrict__ lo) {
  const int i0 = blockIdx.y * 64, j0 = blockIdx.x * 64;
  __shared__ float tb[64][68];
  const int u = threadIdx.x;
#pragma unroll
  for (int it = 0; it < 4; ++it) {
    const int idx = it * 256 + u, rr = idx >> 4, cc = (idx & 15) * 4;
    *(float4*)&tb[rr][cc] = *(const float4*)&R[(size_t)(j0 + rr) * DD + i0 + cc];
  }
  __syncthreads();
#pragma unroll
  for (int it = 0; it < 4; ++it) {
    const int idx = it * 256 + u, rr = idx >> 4, cc = (idx & 15) * 4;
    const float4 v = *(const float4*)&R[(size_t)(i0 + rr) * DD + j0 + cc];
    const float vv[4] = {v.x + tb[cc + 0][rr], v.y + tb[cc + 1][rr],
                         v.z + tb[cc + 2][rr], v.w + tb[cc + 3][rr]};
    f16x4 h4, l4;
#pragma unroll
    for (int j = 0; j < 4; ++j) {
      f16 h = (f16)vv[j];
      h4[j] = h * (f16)64.0f;
      l4[j] = (f16)((vv[j] - (float)h) * 64.0f);
    }
    const size_t o = (size_t)(i0 + rr) * DD + j0 + cc;
    *(f16x4*)&hi[o] = h4;
    *(f16x4*)&lo[o] = l4;
  }
}

// f16 plane transpose
__global__ __launch_bounds__(256)
void k_tr16(const f16* __restrict__ in, f16* __restrict__ o, int dim) {
  const int i0 = blockIdx.y * 64, j0 = blockIdx.x * 64;
  __shared__ f16 tb[64][72];
  const int u = threadIdx.x;
#pragma unroll
  for (int it = 0; it < 2; ++it) {
    const int C = it * 256 + u, row = C >> 3, ch = C & 7;
    *(f16x8*)&tb[row][ch * 8] = *(const f16x8*)&in[(size_t)(i0 + row) * dim + j0 + ch * 8];
  }
  __syncthreads();
#pragma unroll
  for (int it = 0; it < 2; ++it) {
    const int C = it * 256 + u, row = C >> 3, ch = C & 7;
    f16x8 v;
#pragma unroll
    for (int j = 0; j < 8; ++j) v[j] = tb[ch * 8 + j][row];
    *(f16x8*)&o[(size_t)(j0 + row) * dim + i0 + ch * 8] = v;
  }
}

// A2 planes = split(P @ Wi)  ([1024][64])
__global__ __launch_bounds__(256)
void k_pwi(const float* __restrict__ P, const float* __restrict__ Wi,
           f16* __restrict__ A2H, f16* __restrict__ A2L) {
  const int m0 = blockIdx.x * 4;
  __shared__ float Ps[4][1024];
  const int u = threadIdx.x;
#pragma unroll
  for (int i = 0; i < 4; ++i) {
    const int idx = i * 256 + u, mi = idx >> 8, kc = (idx & 255) * 4;
    *(float4*)&Ps[mi][kc] = *(const float4*)&P[(size_t)(m0 + mi) * DD + kc];
  }
  __syncthreads();
  const int n = u & 63, mi = u >> 6;
  float acc = 0.f;
  for (int k = 0; k < DD; ++k) acc += Ps[mi][k] * Wi[(size_t)k * DINN + n];
  split_store(acc, A2H, A2L, (size_t)(m0 + mi) * DINN + n);
}

// MoT planes [c][d] = sum_k P[d][k] * Wo[c][k]   (split-stored transposed)
__global__ __launch_bounds__(256)
void k_pwo(const float* __restrict__ P, const float* __restrict__ Wo_,
           f16* __restrict__ MoTH, f16* __restrict__ MoTL) {
  const int d0 = blockIdx.x * 4;
  __shared__ float Ps[4][1024];
  __shared__ float ws[64][65];
  const int u = threadIdx.x;
#pragma unroll
  for (int i = 0; i < 4; ++i) {
    const int idx = i * 256 + u, mi = idx >> 8, kc = (idx & 255) * 4;
    *(float4*)&Ps[mi][kc] = *(const float4*)&P[(size_t)(d0 + mi) * DD + kc];
  }
  const int c = u & 63, di = u >> 6;
  float acc = 0.f;
  for (int k0 = 0; k0 < DD; k0 += 64) {
    __syncthreads();
#pragma unroll
    for (int i = 0; i < 4; ++i) {
      const int idx = i * 256 + u, cc = idx >> 4, kc = (idx & 15) * 4;
      const float4 v = *(const float4*)&Wo_[(size_t)cc * DD + k0 + kc];
      ws[cc][kc] = v.x; ws[cc][kc + 1] = v.y; ws[cc][kc + 2] = v.z; ws[cc][kc + 3] = v.w;
    }
    __syncthreads();
    for (int kk = 0; kk < 64; ++kk) acc += Ps[di][k0 + kk] * ws[c][kk];
  }
  split_store(acc, MoTH, MoTL, (size_t)c * DD + d0 + di);
}

// cvec = P @ bi ; wave per row
__global__ __launch_bounds__(256)
void k_matvec(const float* __restrict__ P, const float* __restrict__ b,
              float* __restrict__ c) {
  const int row = blockIdx.x * 4 + (threadIdx.x >> 6);
  const int l = threadIdx.x & 63;
  float s = 0.f;
  for (int k = l; k < DD; k += 64) s += P[(size_t)row * DD + k] * b[k];
  for (int o = 32; o; o >>= 1) s += __shfl_down(s, o, 64);
  if (l == 0) c[row] = s;
}

// ---------------------------------------------------------------------------
extern "C" void kernel_launch(void* const* d_in, const int* in_sizes, int n_in,
                              void* d_out, int out_size, void* d_ws, size_t ws_size,
                              hipStream_t stream) {
  (void)in_sizes; (void)n_in; (void)out_size; (void)ws_size;
  const float* x    = (const float*)d_in[0];
  const float* Wi   = (const float*)d_in[1];
  const float* bi   = (const float*)d_in[2];
  const float* P    = (const float*)d_in[3];
  const float* rotW = (const float*)d_in[4];
  const float* F    = (const float*)d_in[5];
  const float* G    = (const float*)d_in[6];
  const float* R    = (const float*)d_in[7];
  const float* Wo   = (const float*)d_in[8];
  const float* bo   = (const float*)d_in[9];
  float* out = (float*)d_out;
  char* w = (char*)d_ws;

  constexpr size_t MB = 1u << 20;
  // h planes (f16, [8192][1024], hi scaled x64, lo = resid x64)
  f16* haH = (f16*)(w + 0 * MB);
  f16* haL = (f16*)(w + 16 * MB);
  f16* hbH = (f16*)(w + 32 * MB);
  f16* hbL = (f16*)(w + 48 * MB);
  // weight planes ([n][k] layout)
  f16* B0tH = (f16*)(w + 64 * MB); f16* B0tL = (f16*)(w + 66 * MB);   // W0^T
  f16* B12tH= (f16*)(w + 68 * MB); f16* B12tL= (f16*)(w + 70 * MB);   // W12^T
  f16* BssH = (f16*)(w + 72 * MB); f16* BssL = (f16*)(w + 74 * MB);   // R+R^T
  f16* B12H = (f16*)(w + 76 * MB); f16* B12L = (f16*)(w + 78 * MB);   // W12
  f16* B0H  = (f16*)(w + 80 * MB); f16* B0L  = (f16*)(w + 82 * MB);   // W0
  f16* BFH  = (f16*)(w + 84 * MB); f16* BFL  = (f16*)(w + 85 * MB + 512 * 1024); // F^T x3
  f16* BGH  = (f16*)(w + 87 * MB); f16* BGL  = (f16*)(w + 88 * MB + 512 * 1024); // G^T x3
  // small planes / vectors
  f16* MoTH   = (f16*)(w + 90 * MB);
  f16* MoTL   = (f16*)(w + 90 * MB + 128 * 1024);
  float* cvec = (float*)(w + 90 * MB + 256 * 1024);
  f16* A2H    = (f16*)(w + 91 * MB);
  f16* A2L    = (f16*)(w + 91 * MB + 128 * 1024);
  f16* xsH    = (f16*)(w + 92 * MB);   // split x planes, natural [b][t][k]
  f16* xsL    = (f16*)(w + 93 * MB);
  // temp W1/W2 split planes alias hb region (dead until first GEMM writes hb)
  f16* W1sH = (f16*)(w + 32 * MB); f16* W1sL = (f16*)(w + 34 * MB);
  f16* W2tH = (f16*)(w + 36 * MB); f16* W2tL = (f16*)(w + 38 * MB);

  const float* W0 = rotW;
  const float* W1 = rotW + (1u << 20);
  const float* W2 = rotW + (2u << 20);

  const dim3 blk256(256);
  const dim3 blk128(128);
  const size_t FGQ = (size_t)512 * 512;

  // ---- precompute: weight splits ----
  k_split     <<<dim3(1024), blk256, 0, stream>>>(W1, W1sH, W1sL);              // W1 [m][k]
  k_splitT    <<<dim3(16, 16), blk256, 0, stream>>>(W2, W2tH, W2tL, DD);        // W2^T [n][k]
  // W12 = W1 @ W2 in split-f16
  k_gemm16<4, 4, false, false, 0><<<dim3(8, 16), blk128, 0, stream>>>(W1sH, W1sL, DD, W2tH, W2tL, DD, B12H, B12L, DD, DD);
  k_tr16      <<<dim3(16, 16), blk256, 0, stream>>>(B12H, B12tH, DD);           // W12^T planes
  k_tr16      <<<dim3(16, 16), blk256, 0, stream>>>(B12L, B12tL, DD);
  k_symm_split<<<dim3(16, 16), blk256, 0, stream>>>(R, BssH, BssL);
  k_splitT    <<<dim3(16, 16), blk256, 0, stream>>>(W0, B0tH, B0tL, DD);        // W0^T
  k_split     <<<dim3(1024), blk256, 0, stream>>>(W0, B0H, B0L);                // W0 as-is
  k_splitT    <<<dim3(8, 8, 3), blk256, 0, stream>>>(F, BFH, BFL, 512);         // F_i^T
  k_splitT    <<<dim3(8, 8, 3), blk256, 0, stream>>>(G, BGH, BGL, 512);         // G_i^T
  k_split     <<<dim3(512), blk256, 0, stream>>>(x, xsH, xsL);                  // x planes
  k_pwi       <<<dim3(256), blk256, 0, stream>>>(P, Wi, A2H, A2L);
  k_pwo       <<<dim3(256), blk256, 0, stream>>>(P, Wo, MoTH, MoTL);
  k_matvec    <<<dim3(256), blk256, 0, stream>>>(P, bi, cvec);

  // ---- main pipeline ----
  // input projection (MFMA, pre-rolled -t via B-row staging)
  k_in_mfma<<<dim3(8, 128), blk256, 0, stream>>>(xsH, xsL, A2H, A2L, cvec, haH, haL);

  // rotor 0 fwd (A pre-rolled, store +t)
  k_gemm16<4, 8, true, false, +1><<<dim3(8, 64), blk128, 0, stream>>>(haH, haL, DD, B0tH, B0tL, DD, hbH, hbL, DD, DD);
  // rotors 1,2 precomposed
  k_gemm16<4, 8, true, false, 0><<<dim3(8, 64), blk128, 0, stream>>>(hbH, hbL, DD, B12tH, B12tL, DD, haH, haL, DD, DD);
  // reversible blocks fwd (in place on ha; h2 = cols 512.., y1 = cols 0..)
  for (int i = 0; i < 3; ++i) {
    k_gemm16<4, 4, false, true, 0><<<dim3(4, 128), blk128, 0, stream>>>(haH + 512, haL + 512, DD, BFH + i * FGQ, BFL + i * FGQ, 512, haH, haL, DD, 512);
    k_gemm16<4, 4, false, true, 0><<<dim3(4, 128), blk128, 0, stream>>>(haH, haL, DD, BGH + i * FGQ, BGL + i * FGQ, 512, haH + 512, haL + 512, DD, 512);
  }
  // reflector
  k_gemm16<4, 8, true, false, 0><<<dim3(8, 64), blk128, 0, stream>>>(haH, haL, DD, BssH, BssL, DD, hbH, hbL, DD, DD);
  // reversible blocks reversed (in place on hb)
  for (int i = 2; i >= 0; --i) {
    k_gemm16<4, 4, false, true, 0><<<dim3(4, 128), blk128, 0, stream>>>(hbH + 512, hbL + 512, DD, BFH + i * FGQ, BFL + i * FGQ, 512, hbH, hbL, DD, 512);
    k_gemm16<4, 4, false, true, 0><<<dim3(4, 128), blk128, 0, stream>>>(hbH, hbL, DD, BGH + i * FGQ, BGL + i * FGQ, 512, hbH + 512, hbL + 512, DD, 512);
  }
  // rotors inverse: W12^T-mult (B = W12 as-is), store pre-rolled (-t)
  k_gemm16<4, 8, true, false, -1><<<dim3(8, 64), blk128, 0, stream>>>(hbH, hbL, DD, B12H, B12L, DD, haH, haL, DD, DD);
  // rotor 0 inverse: W0^T-mult (B = W0 as-is), store +t -> linear
  k_gemm16<4, 8, true, false, +1><<<dim3(8, 64), blk128, 0, stream>>>(haH, haL, DD, B0H, B0L, DD, hbH, hbL, DD, DD);

  // output projection (MFMA on already-split h planes)
  k_out_mfma<<<dim3(128), blk256, 0, stream>>>(hbH, hbL, MoTH, MoTL, bo, out);
}

// Round 11
// 705.890 us; speedup vs baseline: 1.2133x; 1.2133x over previous
//
#include <hip/hip_runtime.h>
#include <math.h>

#define DD 1024
#define MM 8192   // B*S rows
#define SS 128
#define DINN 64
#define DOUTN 64

typedef _Float16 f16;
typedef _Float16 f16x8 __attribute__((ext_vector_type(8)));
typedef _Float16 f16x4 __attribute__((ext_vector_type(4)));
typedef float    f32x4 __attribute__((ext_vector_type(4)));

// direct global->LDS, 16B per lane; LDS base must be wave-uniform
#define GLOAD_LDS(g, l) \
  __builtin_amdgcn_global_load_lds((const __attribute__((address_space(1))) void*)(g), \
                                   (__attribute__((address_space(3))) void*)(l), 16, 0, 0)

// split helpers: store hi' = f16(y)*64, lo' = f16((y - hi)*64); y = hi'/64 + lo'/4096.
__device__ __forceinline__ void split_store(float y, f16* __restrict__ hp, f16* __restrict__ lp, size_t idx) {
  f16 h = (f16)y;
  hp[idx] = h * (f16)64.0f;
  lp[idx] = (f16)((y - (float)h) * 64.0f);
}
__device__ __forceinline__ float join_load(const f16* __restrict__ hp, const f16* __restrict__ lp, size_t idx) {
  return (float)hp[idx] * 0.015625f + (float)lp[idx] * 0.000244140625f;
}

// ---------------------------------------------------------------------------
// Split-f16 MFMA GEMM (R8 geometry: 256 thr / 4 waves, BN=128, BK=32,
// wave-tile (BM/2)x64, MT=BM/32, NT=4).
// PIPE=0: classic loop (stage-all -> reads -> MFMA -> __syncthreads), R8-exact.
// PIPE=1: 4-phase counted-vmcnt schedule (T3+T4 port), R10-race FIXED:
//   per iter: issue pair0(next tile) -> vmcnt(2) -> CERT BARRIER -> read a;
//   then 4 phases {issue pair p (p>=1); read b[p]; barrier; setprio(1);
//   12 MFMA; setprio(0); barrier}.
//   RAW: current-tile reads are issued only AFTER vmcnt certifies all
//   prior-iteration global_load_lds writes landed + barrier (all waves).
//   WAR: every wave's reads are consumed by MFMAs (compiler lgkm waits)
//   before the phase-3 trailing barrier, so next-iter writes into the
//   flipped buffer (issued after that barrier) cannot clobber live reads.
// LDS swizzle s(row)=(row>>1)&3: conflict-free (R7: SQ_LDS_BANK_CONFLICT=0).
// SHIFT: store col = (n + SHIFT*(m>>6)) & 1023 (scalar path).
// EPI:  y = y_old + tanh(acc/4096).
// ---------------------------------------------------------------------------
template<int BM, bool EPI, int SHIFT, bool PIPE>
__global__ __launch_bounds__(256)
void k_gemm16(const f16* __restrict__ Ahi, const f16* __restrict__ Alo, int lda,
              const f16* __restrict__ Bhi, const f16* __restrict__ Blo, int ldb,
              f16* __restrict__ Chi, f16* __restrict__ Clo, int ldc, int K) {
  constexpr int MT = BM / 32;      // 16-row m-tiles per wave
  constexpr int AI = BM / 64;      // A staging iters (256 chunks each, per plane)
  __shared__ f16 sA[2][2][BM * 32];
  __shared__ f16 sB[2][2][128 * 32];

  // XCD-aware swizzle (nwg % 8 == 0 for all our grids)
  const int nwg = gridDim.x * gridDim.y;
  int wg = blockIdx.y * gridDim.x + blockIdx.x;
  wg = (wg & 7) * (nwg >> 3) + (wg >> 3);
  const int bx = wg % gridDim.x, by = wg / gridDim.x;

  const int col0 = bx * 128, row0 = by * BM;
  const int u = threadIdx.x, lane = u & 63, wv = u >> 6;
  const int mh = (wv >> 1) * (BM >> 1);
  const int nh = (wv & 1) * 64;

  unsigned aoff[AI], boff[2];
  unsigned dstA[AI], dstB[2];
#pragma unroll
  for (int i = 0; i < AI; ++i) {
    const int P = i * 256 + u;
    const int row = P >> 2, kc = (P & 3) ^ ((row >> 1) & 3);
    aoff[i] = (unsigned)(row0 + row) * lda + kc * 8;
    dstA[i] = (i * 256 + wv * 64) * 8;
  }
#pragma unroll
  for (int i = 0; i < 2; ++i) {
    const int P = i * 256 + u;
    const int row = P >> 2, kc = (P & 3) ^ ((row >> 1) & 3);
    boff[i] = (unsigned)(col0 + row) * ldb + kc * 8;
    dstB[i] = (i * 256 + wv * 64) * 8;
  }

  const int frag = (lane & 15) * 32 + (((lane >> 4) ^ ((lane >> 1) & 3)) * 8);

  f32x4 acc[MT][4];
#pragma unroll
  for (int i = 0; i < MT; ++i)
#pragma unroll
    for (int j = 0; j < 4; ++j) acc[i][j] = (f32x4){0.f, 0.f, 0.f, 0.f};

  auto stage = [&](int b, int k0) {
#pragma unroll
    for (int i = 0; i < AI; ++i) {
      GLOAD_LDS(Ahi + aoff[i] + k0, &sA[b][0][dstA[i]]);
      GLOAD_LDS(Alo + aoff[i] + k0, &sA[b][1][dstA[i]]);
    }
#pragma unroll
    for (int i = 0; i < 2; ++i) {
      GLOAD_LDS(Bhi + boff[i] + k0, &sB[b][0][dstB[i]]);
      GLOAD_LDS(Blo + boff[i] + k0, &sB[b][1][dstB[i]]);
    }
  };
  // stage pair p (PIPE path): p in [0, AI+2): A pairs first, then B pairs.
  auto stage_pair = [&](int b, int k0, int p) {
    if (p < AI) {
      GLOAD_LDS(Ahi + aoff[p] + k0, &sA[b][0][dstA[p]]);
      GLOAD_LDS(Alo + aoff[p] + k0, &sA[b][1][dstA[p]]);
    } else {
      const int i = p - AI;
      GLOAD_LDS(Bhi + boff[i] + k0, &sB[b][0][dstB[i]]);
      GLOAD_LDS(Blo + boff[i] + k0, &sB[b][1][dstB[i]]);
    }
  };

  const int niter = K >> 5;
  int buf = 0;

  if constexpr (!PIPE) {
    stage(0, 0);
    __syncthreads();
    for (int it = 0; it < niter; ++it) {
      if (it + 1 < niter) stage(buf ^ 1, (it + 1) << 5);
      f16x8 aH[MT], aL[MT], bH[4], bL[4];
#pragma unroll
      for (int mt = 0; mt < MT; ++mt) {
        aH[mt] = *(const f16x8*)&sA[buf][0][(mh + mt * 16) * 32 + frag];
        aL[mt] = *(const f16x8*)&sA[buf][1][(mh + mt * 16) * 32 + frag];
      }
#pragma unroll
      for (int nt = 0; nt < 4; ++nt) {
        bH[nt] = *(const f16x8*)&sB[buf][0][(nh + nt * 16) * 32 + frag];
        bL[nt] = *(const f16x8*)&sB[buf][1][(nh + nt * 16) * 32 + frag];
      }
#pragma unroll
      for (int mt = 0; mt < MT; ++mt)
#pragma unroll
        for (int nt = 0; nt < 4; ++nt) {
          acc[mt][nt] = __builtin_amdgcn_mfma_f32_16x16x32_f16(aH[mt], bH[nt], acc[mt][nt], 0, 0, 0);
          acc[mt][nt] = __builtin_amdgcn_mfma_f32_16x16x32_f16(aH[mt], bL[nt], acc[mt][nt], 0, 0, 0);
          acc[mt][nt] = __builtin_amdgcn_mfma_f32_16x16x32_f16(aL[mt], bH[nt], acc[mt][nt], 0, 0, 0);
        }
      __syncthreads();
      buf ^= 1;
    }
  } else {
    stage(0, 0);
    asm volatile("s_waitcnt vmcnt(0)" ::: "memory");
    __builtin_amdgcn_s_barrier();
    for (int it = 0; it < niter; ++it) {
      const int nk = (it + 1) << 5;
      const bool pf = (it + 1 < niter);
      // ---- cert: issue pair 0 for next tile, then certify current landed ----
      if (pf) {
        stage_pair(buf ^ 1, nk, 0);
        asm volatile("s_waitcnt vmcnt(2)" ::: "memory");
      } else {
        asm volatile("s_waitcnt vmcnt(0)" ::: "memory");
      }
      __builtin_amdgcn_s_barrier();   // all waves certified BEFORE any read
      f16x8 aH[MT], aL[MT];
#pragma unroll
      for (int mt = 0; mt < MT; ++mt) {
        aH[mt] = *(const f16x8*)&sA[buf][0][(mh + mt * 16) * 32 + frag];
        aL[mt] = *(const f16x8*)&sA[buf][1][(mh + mt * 16) * 32 + frag];
      }
      // ---- 4 phases: stage pair p (p>=1); read b[p]; barrier; MFMA; barrier
#pragma unroll
      for (int p = 0; p < 4; ++p) {
        if (pf && p >= 1 && p < AI + 2) stage_pair(buf ^ 1, nk, p);
        const f16x8 bH = *(const f16x8*)&sB[buf][0][(nh + p * 16) * 32 + frag];
        const f16x8 bL = *(const f16x8*)&sB[buf][1][(nh + p * 16) * 32 + frag];
        __builtin_amdgcn_s_barrier();
        __builtin_amdgcn_s_setprio(1);
#pragma unroll
        for (int mt = 0; mt < MT; ++mt) {
          acc[mt][p] = __builtin_amdgcn_mfma_f32_16x16x32_f16(aH[mt], bH, acc[mt][p], 0, 0, 0);
          acc[mt][p] = __builtin_amdgcn_mfma_f32_16x16x32_f16(aH[mt], bL, acc[mt][p], 0, 0, 0);
          acc[mt][p] = __builtin_amdgcn_mfma_f32_16x16x32_f16(aL[mt], bH, acc[mt][p], 0, 0, 0);
        }
        __builtin_amdgcn_s_setprio(0);
        __builtin_amdgcn_s_barrier();
      }
      buf ^= 1;
    }
  }

  if constexpr (SHIFT == 0) {
    // ---- vectorized epilogue: per-wave LDS transpose staging (reuse sB) ----
    f16* eH = ((f16*)sB) + wv * (16 * 84 * 2);
    f16* eL = eH + 16 * 84;
    const int lrow4 = (lane >> 4) << 2;
    const int lcol = lane & 15;
#pragma unroll
    for (int mt = 0; mt < MT; ++mt) {
#pragma unroll
      for (int nt = 0; nt < 4; ++nt) {
        const f32x4 a = acc[mt][nt];
#pragma unroll
        for (int r = 0; r < 4; ++r) {
          const float y = a[r] * 0.000244140625f;
          const f16 h = (f16)y;
          const int o = (lrow4 + r) * 84 + nt * 16 + lcol;
          eH[o] = h * (f16)64.0f;
          eL[o] = (f16)((y - (float)h) * 64.0f);
        }
      }
#pragma unroll
      for (int j = 0; j < 2; ++j) {
        const int idx = j * 64 + lane;
        const int row = idx >> 3, ch = idx & 7;
        const f16x8 vh = *(const f16x8*)&eH[row * 84 + ch * 8];
        const f16x8 vl = *(const f16x8*)&eL[row * 84 + ch * 8];
        const int m = row0 + mh + mt * 16 + row;
        const size_t gi = (size_t)m * ldc + col0 + nh + ch * 8;
        if (EPI) {
          const f16x8 oh = *(const f16x8*)&Chi[gi];
          const f16x8 ol = *(const f16x8*)&Clo[gi];
          f16x8 rh, rl;
#pragma unroll
          for (int q = 0; q < 8; ++q) {
            const float yn = (float)vh[q] * 0.015625f + (float)vl[q] * 0.000244140625f;
            const float y  = (float)oh[q] * 0.015625f + (float)ol[q] * 0.000244140625f + tanhf(yn);
            const f16 h = (f16)y;
            rh[q] = h * (f16)64.0f;
            rl[q] = (f16)((y - (float)h) * 64.0f);
          }
          *(f16x8*)&Chi[gi] = rh;
          *(f16x8*)&Clo[gi] = rl;
        } else {
          *(f16x8*)&Chi[gi] = vh;
          *(f16x8*)&Clo[gi] = vl;
        }
      }
    }
  } else {
    // ---- scalar epilogue (rotor shift folded into col index) ----
#pragma unroll
    for (int mt = 0; mt < MT; ++mt)
#pragma unroll
      for (int nt = 0; nt < 4; ++nt) {
        const f32x4 a = acc[mt][nt];
        const int n_base = col0 + nh + nt * 16 + (lane & 15);
#pragma unroll
        for (int r = 0; r < 4; ++r) {
          const int m = row0 + mh + mt * 16 + ((lane >> 4) << 2) + r;
          int n = (n_base + SHIFT * (m >> 6) + 2048) & (DD - 1);
          const size_t idx = (size_t)m * ldc + n;
          float y = a[r] * 0.000244140625f;
          if (EPI) y = join_load(Chi, Clo, idx) + tanhf(y);
          split_store(y, Chi, Clo, idx);
        }
      }
  }
}

// ---------------------------------------------------------------------------
// input projection as MFMA GEMM:
//   h0_pre[r][j] = sum_k x[b][t][k]*A2[(j+t)&1023][k] + cvec[(j+t)&1023]
//   (r = t*64+b; t = blockIdx.y uniform since BM=64)
// ---------------------------------------------------------------------------
__global__ __launch_bounds__(256)
void k_in_mfma(const f16* __restrict__ xH, const f16* __restrict__ xL,
               const f16* __restrict__ A2H, const f16* __restrict__ A2L,
               const float* __restrict__ cvec,
               f16* __restrict__ hH, f16* __restrict__ hL) {
  __shared__ f16 sA[2][2][64 * 32];
  __shared__ f16 sB[2][2][128 * 32];
  const int bx = blockIdx.x, by = blockIdx.y;   // n-block, m-block(=t)
  const int col0 = bx * 128, row0 = by * 64, t = by;
  const int u = threadIdx.x, lane = u & 63, wv = u >> 6;
  const int mh = (wv >> 1) * 32;
  const int nh = (wv & 1) * 64;

  unsigned aoff, boff[2], dstA, dstB[2];
  {
    const int row = u >> 2, kc = (u & 3) ^ ((row >> 1) & 3);
    aoff = (unsigned)(row * SS + t) * DINN + kc * 8;
    dstA = (unsigned)(wv * 64) * 8;
  }
#pragma unroll
  for (int i = 0; i < 2; ++i) {
    const int P = i * 256 + u;
    const int row = P >> 2, kc = (P & 3) ^ ((row >> 1) & 3);
    const int src = (col0 + row + t) & (DD - 1);
    boff[i] = (unsigned)src * DINN + kc * 8;
    dstB[i] = (i * 256 + wv * 64) * 8;
  }

  const int frag = (lane & 15) * 32 + (((lane >> 4) ^ ((lane >> 1) & 3)) * 8);

  f32x4 acc[2][4];
#pragma unroll
  for (int i = 0; i < 2; ++i)
#pragma unroll
    for (int j = 0; j < 4; ++j) acc[i][j] = (f32x4){0.f, 0.f, 0.f, 0.f};

  auto stage = [&](int b, int k0) {
    GLOAD_LDS(xH + aoff + k0, &sA[b][0][dstA]);
    GLOAD_LDS(xL + aoff + k0, &sA[b][1][dstA]);
#pragma unroll
    for (int i = 0; i < 2; ++i) {
      GLOAD_LDS(A2H + boff[i] + k0, &sB[b][0][dstB[i]]);
      GLOAD_LDS(A2L + boff[i] + k0, &sB[b][1][dstB[i]]);
    }
  };

  stage(0, 0);
  __syncthreads();
  int buf = 0;
#pragma unroll
  for (int it = 0; it < 2; ++it) {
    if (it == 0) stage(1, 32);
    f16x8 aH[2], aL[2], bH[4], bL[4];
#pragma unroll
    for (int mt = 0; mt < 2; ++mt) {
      aH[mt] = *(const f16x8*)&sA[buf][0][(mh + mt * 16) * 32 + frag];
      aL[mt] = *(const f16x8*)&sA[buf][1][(mh + mt * 16) * 32 + frag];
    }
#pragma unroll
    for (int nt = 0; nt < 4; ++nt) {
      bH[nt] = *(const f16x8*)&sB[buf][0][(nh + nt * 16) * 32 + frag];
      bL[nt] = *(const f16x8*)&sB[buf][1][(nh + nt * 16) * 32 + frag];
    }
#pragma unroll
    for (int mt = 0; mt < 2; ++mt)
#pragma unroll
      for (int nt = 0; nt < 4; ++nt) {
        acc[mt][nt] = __builtin_amdgcn_mfma_f32_16x16x32_f16(aH[mt], bH[nt], acc[mt][nt], 0, 0, 0);
        acc[mt][nt] = __builtin_amdgcn_mfma_f32_16x16x32_f16(aH[mt], bL[nt], acc[mt][nt], 0, 0, 0);
        acc[mt][nt] = __builtin_amdgcn_mfma_f32_16x16x32_f16(aL[mt], bH[nt], acc[mt][nt], 0, 0, 0);
      }
    __syncthreads();
    buf ^= 1;
  }

  f16* eH = ((f16*)sB) + wv * (16 * 84 * 2);
  f16* eL = eH + 16 * 84;
  const int lrow4 = (lane >> 4) << 2;
  const int lcol = lane & 15;
#pragma unroll
  for (int mt = 0; mt < 2; ++mt) {
#pragma unroll
    for (int nt = 0; nt < 4; ++nt) {
      const f32x4 a = acc[mt][nt];
      const int n = col0 + nh + nt * 16 + lcol;
      const float cv = cvec[(n + t) & (DD - 1)];
#pragma unroll
      for (int r = 0; r < 4; ++r) {
        const float y = a[r] * 0.000244140625f + cv;
        const f16 h = (f16)y;
        const int o = (lrow4 + r) * 84 + nt * 16 + lcol;
        eH[o] = h * (f16)64.0f;
        eL[o] = (f16)((y - (float)h) * 64.0f);
      }
    }
#pragma unroll
    for (int j = 0; j < 2; ++j) {
      const int idx = j * 64 + lane;
      const int row = idx >> 3, ch = idx & 7;
      const f16x8 vh = *(const f16x8*)&eH[row * 84 + ch * 8];
      const f16x8 vl = *(const f16x8*)&eL[row * 84 + ch * 8];
      const int m = row0 + mh + mt * 16 + row;
      const size_t gi = (size_t)m * DD + col0 + nh + ch * 8;
      *(f16x8*)&hH[gi] = vh;
      *(f16x8*)&hL[gi] = vl;
    }
  }
}

// ---------------------------------------------------------------------------
// output projection as MFMA GEMM: out[b][t][c] = (h @ MoT^T)[r][c] + bo[c]
// ---------------------------------------------------------------------------
__global__ __launch_bounds__(256)
void k_out_mfma(const f16* __restrict__ Ahi, const f16* __restrict__ Alo,
                const f16* __restrict__ Bhi, const f16* __restrict__ Blo,
                const float* __restrict__ bo, float* __restrict__ out) {
  __shared__ f16 sA[2][2][64 * 32];
  __shared__ f16 sB[2][2][64 * 32];
  const int row0 = blockIdx.x * 64;
  const int u = threadIdx.x, lane = u & 63, wv = u >> 6;
  const int mh = (wv >> 1) * 32, nh = (wv & 1) * 32;

  const int srow = u >> 2, skc = (u & 3) ^ ((srow >> 1) & 3);
  const unsigned aoff = (unsigned)(row0 + srow) * DD + skc * 8;
  const unsigned boff = (unsigned)srow * DD + skc * 8;
  const unsigned dst = (unsigned)(wv * 64) * 8;

  const int frag = (lane & 15) * 32 + (((lane >> 4) ^ ((lane >> 1) & 3)) * 8);

  f32x4 acc[2][2];
#pragma unroll
  for (int i = 0; i < 2; ++i)
#pragma unroll
    for (int j = 0; j < 2; ++j) acc[i][j] = (f32x4){0.f, 0.f, 0.f, 0.f};

  auto stage = [&](int b, int k0) {
    GLOAD_LDS(Ahi + aoff + k0, &sA[b][0][dst]);
    GLOAD_LDS(Alo + aoff + k0, &sA[b][1][dst]);
    GLOAD_LDS(Bhi + boff + k0, &sB[b][0][dst]);
    GLOAD_LDS(Blo + boff + k0, &sB[b][1][dst]);
  };

  stage(0, 0);
  __syncthreads();
  int buf = 0;
  for (int it = 0; it < 32; ++it) {
    if (it + 1 < 32) stage(buf ^ 1, (it + 1) << 5);
    f16x8 aH[2], aL[2], bH[2], bL[2];
#pragma unroll
    for (int mt = 0; mt < 2; ++mt) {
      aH[mt] = *(const f16x8*)&sA[buf][0][(mh + mt * 16) * 32 + frag];
      aL[mt] = *(const f16x8*)&sA[buf][1][(mh + mt * 16) * 32 + frag];
    }
#pragma unroll
    for (int nt = 0; nt < 2; ++nt) {
      bH[nt] = *(const f16x8*)&sB[buf][0][(nh + nt * 16) * 32 + frag];
      bL[nt] = *(const f16x8*)&sB[buf][1][(nh + nt * 16) * 32 + frag];
    }
#pragma unroll
    for (int mt = 0; mt < 2; ++mt)
#pragma unroll
      for (int nt = 0; nt < 2; ++nt) {
        acc[mt][nt] = __builtin_amdgcn_mfma_f32_16x16x32_f16(aH[mt], bH[nt], acc[mt][nt], 0, 0, 0);
        acc[mt][nt] = __builtin_amdgcn_mfma_f32_16x16x32_f16(aH[mt], bL[nt], acc[mt][nt], 0, 0, 0);
        acc[mt][nt] = __builtin_amdgcn_mfma_f32_16x16x32_f16(aL[mt], bH[nt], acc[mt][nt], 0, 0, 0);
      }
    __syncthreads();
    buf ^= 1;
  }

#pragma unroll
  for (int mt = 0; mt < 2; ++mt)
#pragma unroll
    for (int nt = 0; nt < 2; ++nt) {
      const f32x4 a = acc[mt][nt];
      const int c = nh + nt * 16 + (lane & 15);
      const float bias = bo[c];
#pragma unroll
      for (int r = 0; r < 4; ++r) {
        const int m = row0 + mh + mt * 16 + ((lane >> 4) << 2) + r;
        const int t = m >> 6, b = m & 63;
        out[((size_t)b * SS + t) * DOUTN + c] = a[r] * 0.000244140625f + bias;
      }
    }
}

// ---------------------------------------------------------------------------
// precompute: splits / transposes
// ---------------------------------------------------------------------------
__global__ __launch_bounds__(256)
void k_split(const float* __restrict__ src, f16* __restrict__ hi, f16* __restrict__ lo) {
  const int i = blockIdx.x * 256 + threadIdx.x;
  const float4 v = ((const float4*)src)[i];
  f16x4 h4, l4;
  const float vv[4] = {v.x, v.y, v.z, v.w};
#pragma unroll
  for (int j = 0; j < 4; ++j) {
    f16 h = (f16)vv[j];
    h4[j] = h * (f16)64.0f;
    l4[j] = (f16)((vv[j] - (float)h) * 64.0f);
  }
  ((f16x4*)hi)[i] = h4;
  ((f16x4*)lo)[i] = l4;
}

// transpose + split: src fp32 [dim][dim] (z-batched) -> planes = src^T
__global__ __launch_bounds__(256)
void k_splitT(const float* __restrict__ src, f16* __restrict__ hi, f16* __restrict__ lo, int dim) {
  const size_t zo = (size_t)blockIdx.z * dim * dim;
  src += zo; hi += zo; lo += zo;
  const int i0 = blockIdx.y * 64, j0 = blockIdx.x * 64;
  __shared__ float tb[64][68];
  const int u = threadIdx.x;
#pragma unroll
  for (int it = 0; it < 4; ++it) {
    const int idx = it * 256 + u, rr = idx >> 4, cc = (idx & 15) * 4;
    *(float4*)&tb[rr][cc] = *(const float4*)&src[(size_t)(i0 + rr) * dim + j0 + cc];
  }
  __syncthreads();
#pragma unroll
  for (int it = 0; it < 4; ++it) {
    const int idx = it * 256 + u, rr = idx >> 4, cc = (idx & 15) * 4;
    f16x4 h4, l4;
#pragma unroll
    for (int j = 0; j < 4; ++j) {
      const float y = tb[cc + j][rr];
      f16 h = (f16)y;
      h4[j] = h * (f16)64.0f;
      l4[j] = (f16)((y - (float)h) * 64.0f);
    }
    const size_t o = (size_t)(j0 + rr) * dim + i0 + cc;
    *(f16x4*)&hi[o] = h4;
    *(f16x4*)&lo[o] = l4;
  }
}

// S = R + R^T, split-stored (symmetric => [n][k] fine)
__global__ __launch_bounds__(256)
void k_symm_split(const float* __restrict__ R, f16* __restrict__ hi, f16* __restrict__ lo) {
  const int i0 = blockIdx.y * 64, j0 = blockIdx.x * 64;
  __shared__ float tb[64][68];
  const int u = threadIdx.x;
#pragma unroll
  for (int it = 0; it < 4; ++it) {
    const int idx = it * 256 + u, rr = idx >> 4, cc = (idx & 15) * 4;
    *(float4*)&tb[rr][cc] = *(const float4*)&R[(size_t)(j0 + rr) * DD + i0 + cc];
  }
  __syncthreads();
#pragma unroll
  for (int it = 0; it < 4; ++it) {
    const int idx = it * 256 + u, rr = idx >> 4, cc = (idx & 15) * 4;
    const float4 v = *(const float4*)&R[(size_t)(i0 + rr) * DD + j0 + cc];
    const float vv[4] = {v.x + tb[cc + 0][rr], v.y + tb[cc + 1][rr],
                         v.z + tb[cc + 2][rr], v.w + tb[cc + 3][rr]};
    f16x4 h4, l4;
#pragma unroll
    for (int j = 0; j < 4; ++j) {
      f16 h = (f16)vv[j];
      h4[j] = h * (f16)64.0f;
      l4[j] = (f16)((vv[j] - (float)h) * 64.0f);
    }
    const size_t o = (size_t)(i0 + rr) * DD + j0 + cc;
    *(f16x4*)&hi[o] = h4;
    *(f16x4*)&lo[o] = l4;
  }
}

// f16 plane transpose
__global__ __launch_bounds__(256)
void k_tr16(const f16* __restrict__ in, f16* __restrict__ o, int dim) {
  const int i0 = blockIdx.y * 64, j0 = blockIdx.x * 64;
  __shared__ f16 tb[64][72];
  const int u = threadIdx.x;
#pragma unroll
  for (int it = 0; it < 2; ++it) {
    const int C = it * 256 + u, row = C >> 3, ch = C & 7;
    *(f16x8*)&tb[row][ch * 8] = *(const f16x8*)&in[(size_t)(i0 + row) * dim + j0 + ch * 8];
  }
  __syncthreads();
#pragma unroll
  for (int it = 0; it < 2; ++it) {
    const int C = it * 256 + u, row = C >> 3, ch = C & 7;
    f16x8 v;
#pragma unroll
    for (int j = 0; j < 8; ++j) v[j] = tb[ch * 8 + j][row];
    *(f16x8*)&o[(size_t)(j0 + row) * dim + i0 + ch * 8] = v;
  }
}

// A2 planes = split(P @ Wi)  ([1024][64])
__global__ __launch_bounds__(256)
void k_pwi(const float* __restrict__ P, const float* __restrict__ Wi,
           f16* __restrict__ A2H, f16* __restrict__ A2L) {
  const int m0 = blockIdx.x * 4;
  __shared__ float Ps[4][1024];
  const int u = threadIdx.x;
#pragma unroll
  for (int i = 0; i < 4; ++i) {
    const int idx = i * 256 + u, mi = idx >> 8, kc = (idx & 255) * 4;
    *(float4*)&Ps[mi][kc] = *(const float4*)&P[(size_t)(m0 + mi) * DD + kc];
  }
  __syncthreads();
  const int n = u & 63, mi = u >> 6;
  float acc = 0.f;
  for (int k = 0; k < DD; ++k) acc += Ps[mi][k] * Wi[(size_t)k * DINN + n];
  split_store(acc, A2H, A2L, (size_t)(m0 + mi) * DINN + n);
}

// MoT planes [c][d] = sum_k P[d][k] * Wo[c][k]   (split-stored transposed)
__global__ __launch_bounds__(256)
void k_pwo(const float* __restrict__ P, const float* __restrict__ Wo_,
           f16* __restrict__ MoTH, f16* __restrict__ MoTL) {
  const int d0 = blockIdx.x * 4;
  __shared__ float Ps[4][1024];
  __shared__ float ws[64][65];
  const int u = threadIdx.x;
#pragma unroll
  for (int i = 0; i < 4; ++i) {
    const int idx = i * 256 + u, mi = idx >> 8, kc = (idx & 255) * 4;
    *(float4*)&Ps[mi][kc] = *(const float4*)&P[(size_t)(d0 + mi) * DD + kc];
  }
  const int c = u & 63, di = u >> 6;
  float acc = 0.f;
  for (int k0 = 0; k0 < DD; k0 += 64) {
    __syncthreads();
#pragma unroll
    for (int i = 0; i < 4; ++i) {
      const int idx = i * 256 + u, cc = idx >> 4, kc = (idx & 15) * 4;
      const float4 v = *(const float4*)&Wo_[(size_t)cc * DD + k0 + kc];
      ws[cc][kc] = v.x; ws[cc][kc + 1] = v.y; ws[cc][kc + 2] = v.z; ws[cc][kc + 3] = v.w;
    }
    __syncthreads();
    for (int kk = 0; kk < 64; ++kk) acc += Ps[di][k0 + kk] * ws[c][kk];
  }
  split_store(acc, MoTH, MoTL, (size_t)c * DD + d0 + di);
}

// cvec = P @ bi ; wave per row
__global__ __launch_bounds__(256)
void k_matvec(const float* __restrict__ P, const float* __restrict__ b,
              float* __restrict__ c) {
  const int row = blockIdx.x * 4 + (threadIdx.x >> 6);
  const int l = threadIdx.x & 63;
  float s = 0.f;
  for (int k = l; k < DD; k += 64) s += P[(size_t)row * DD + k] * b[k];
  for (int o = 32; o; o >>= 1) s += __shfl_down(s, o, 64);
  if (l == 0) c[row] = s;
}

// ---------------------------------------------------------------------------
extern "C" void kernel_launch(void* const* d_in, const int* in_sizes, int n_in,
                              void* d_out, int out_size, void* d_ws, size_t ws_size,
                              hipStream_t stream) {
  (void)in_sizes; (void)n_in; (void)out_size; (void)ws_size;
  const float* x    = (const float*)d_in[0];
  const float* Wi   = (const float*)d_in[1];
  const float* bi   = (const float*)d_in[2];
  const float* P    = (const float*)d_in[3];
  const float* rotW = (const float*)d_in[4];
  const float* F    = (const float*)d_in[5];
  const float* G    = (const float*)d_in[6];
  const float* R    = (const float*)d_in[7];
  const float* Wo   = (const float*)d_in[8];
  const float* bo   = (const float*)d_in[9];
  float* out = (float*)d_out;
  char* w = (char*)d_ws;

  constexpr size_t MB = 1u << 20;
  // h planes (f16, [8192][1024], hi scaled x64, lo = resid x64)
  f16* haH = (f16*)(w + 0 * MB);
  f16* haL = (f16*)(w + 16 * MB);
  f16* hbH = (f16*)(w + 32 * MB);
  f16* hbL = (f16*)(w + 48 * MB);
  // weight planes ([n][k] layout)
  f16* B0tH = (f16*)(w + 64 * MB); f16* B0tL = (f16*)(w + 66 * MB);   // W0^T
  f16* B12tH= (f16*)(w + 68 * MB); f16* B12tL= (f16*)(w + 70 * MB);   // W12^T
  f16* BssH = (f16*)(w + 72 * MB); f16* BssL = (f16*)(w + 74 * MB);   // R+R^T
  f16* B12H = (f16*)(w + 76 * MB); f16* B12L = (f16*)(w + 78 * MB);   // W12
  f16* B0H  = (f16*)(w + 80 * MB); f16* B0L  = (f16*)(w + 82 * MB);   // W0
  f16* BFH  = (f16*)(w + 84 * MB); f16* BFL  = (f16*)(w + 85 * MB + 512 * 1024); // F^T x3
  f16* BGH  = (f16*)(w + 87 * MB); f16* BGL  = (f16*)(w + 88 * MB + 512 * 1024); // G^T x3
  // small planes / vectors
  f16* MoTH   = (f16*)(w + 90 * MB);
  f16* MoTL   = (f16*)(w + 90 * MB + 128 * 1024);
  float* cvec = (float*)(w + 90 * MB + 256 * 1024);
  f16* A2H    = (f16*)(w + 91 * MB);
  f16* A2L    = (f16*)(w + 91 * MB + 128 * 1024);
  f16* xsH    = (f16*)(w + 92 * MB);   // split x planes, natural [b][t][k]
  f16* xsL    = (f16*)(w + 93 * MB);
  // temp W1/W2 split planes alias hb region (dead until first GEMM writes hb)
  f16* W1sH = (f16*)(w + 32 * MB); f16* W1sL = (f16*)(w + 34 * MB);
  f16* W2tH = (f16*)(w + 36 * MB); f16* W2tL = (f16*)(w + 38 * MB);

  const float* W0 = rotW;
  const float* W1 = rotW + (1u << 20);
  const float* W2 = rotW + (2u << 20);

  const dim3 blk256(256);
  const size_t FGQ = (size_t)512 * 512;

  // ---- precompute: weight splits ----
  k_split     <<<dim3(1024), blk256, 0, stream>>>(W1, W1sH, W1sL);              // W1 [m][k]
  k_splitT    <<<dim3(16, 16), blk256, 0, stream>>>(W2, W2tH, W2tL, DD);        // W2^T [n][k]
  // W12 = W1 @ W2 in split-f16 (classic loop)
  k_gemm16<64, false, 0, false><<<dim3(8, 16), blk256, 0, stream>>>(W1sH, W1sL, DD, W2tH, W2tL, DD, B12H, B12L, DD, DD);
  k_tr16      <<<dim3(16, 16), blk256, 0, stream>>>(B12H, B12tH, DD);           // W12^T planes
  k_tr16      <<<dim3(16, 16), blk256, 0, stream>>>(B12L, B12tL, DD);
  k_symm_split<<<dim3(16, 16), blk256, 0, stream>>>(R, BssH, BssL);
  k_splitT    <<<dim3(16, 16), blk256, 0, stream>>>(W0, B0tH, B0tL, DD);        // W0^T
  k_split     <<<dim3(1024), blk256, 0, stream>>>(W0, B0H, B0L);                // W0 as-is
  k_splitT    <<<dim3(8, 8, 3), blk256, 0, stream>>>(F, BFH, BFL, 512);         // F_i^T
  k_splitT    <<<dim3(8, 8, 3), blk256, 0, stream>>>(G, BGH, BGL, 512);         // G_i^T
  k_split     <<<dim3(512), blk256, 0, stream>>>(x, xsH, xsL);                  // x planes
  k_pwi       <<<dim3(256), blk256, 0, stream>>>(P, Wi, A2H, A2L);
  k_pwo       <<<dim3(256), blk256, 0, stream>>>(P, Wo, MoTH, MoTL);
  k_matvec    <<<dim3(256), blk256, 0, stream>>>(P, bi, cvec);

  // ---- main pipeline ----
  // input projection (MFMA, pre-rolled -t via B-row staging)
  k_in_mfma<<<dim3(8, 128), blk256, 0, stream>>>(xsH, xsL, A2H, A2L, cvec, haH, haL);

  // rotor 0 fwd (A pre-rolled, store +t) — PIPE=1 4-phase schedule
  k_gemm16<128, false, +1, true><<<dim3(8, 64), blk256, 0, stream>>>(haH, haL, DD, B0tH, B0tL, DD, hbH, hbL, DD, DD);
  // rotors 1,2 precomposed
  k_gemm16<128, false, 0, true><<<dim3(8, 64), blk256, 0, stream>>>(hbH, hbL, DD, B12tH, B12tL, DD, haH, haL, DD, DD);
  // reversible blocks fwd (classic loop, in place on ha)
  for (int i = 0; i < 3; ++i) {
    k_gemm16<64, true, 0, false><<<dim3(4, 128), blk256, 0, stream>>>(haH + 512, haL + 512, DD, BFH + i * FGQ, BFL + i * FGQ, 512, haH, haL, DD, 512);
    k_gemm16<64, true, 0, false><<<dim3(4, 128), blk256, 0, stream>>>(haH, haL, DD, BGH + i * FGQ, BGL + i * FGQ, 512, haH + 512, haL + 512, DD, 512);
  }
  // reflector
  k_gemm16<128, false, 0, true><<<dim3(8, 64), blk256, 0, stream>>>(haH, haL, DD, BssH, BssL, DD, hbH, hbL, DD, DD);
  // reversible blocks reversed (classic loop, in place on hb)
  for (int i = 2; i >= 0; --i) {
    k_gemm16<64, true, 0, false><<<dim3(4, 128), blk256, 0, stream>>>(hbH + 512, hbL + 512, DD, BFH + i * FGQ, BFL + i * FGQ, 512, hbH, hbL, DD, 512);
    k_gemm16<64, true, 0, false><<<dim3(4, 128), blk256, 0, stream>>>(hbH, hbL, DD, BGH + i * FGQ, BGL + i * FGQ, 512, hbH + 512, hbL + 512, DD, 512);
  }
  // rotors inverse: W12^T-mult (B = W12 as-is), store pre-rolled (-t)
  k_gemm16<128, false, -1, true><<<dim3(8, 64), blk256, 0, stream>>>(hbH, hbL, DD, B12H, B12L, DD, haH, haL, DD, DD);
  // rotor 0 inverse: W0^T-mult (B = W0 as-is), store +t -> linear
  k_gemm16<128, false, +1, true><<<dim3(8, 64), blk256, 0, stream>>>(haH, haL, DD, B0H, B0L, DD, hbH, hbL, DD, DD);

  // output projection (MFMA on already-split h planes)
  k_out_mfma<<<dim3(128), blk256, 0, stream>>>(hbH, hbL, MoTH, MoTL, bo, out);
}

// Round 12
// 559.350 us; speedup vs baseline: 1.5312x; 1.2620x over previous
//
#include <hip/hip_runtime.h>
#include <math.h>

#define DD 1024
#define MM 8192   // B*S rows
#define SS 128
#define DINN 64
#define DOUTN 64

typedef _Float16 f16;
typedef _Float16 f16x8 __attribute__((ext_vector_type(8)));
typedef _Float16 f16x4 __attribute__((ext_vector_type(4)));
typedef float    f32x4 __attribute__((ext_vector_type(4)));

// direct global->LDS, 16B per lane; LDS base must be wave-uniform
#define GLOAD_LDS(g, l) \
  __builtin_amdgcn_global_load_lds((const __attribute__((address_space(1))) void*)(g), \
                                   (__attribute__((address_space(3))) void*)(l), 16, 0, 0)

// split helpers: store hi' = f16(y)*64, lo' = f16((y - hi)*64); y = hi'/64 + lo'/64.
__device__ __forceinline__ void split_store(float y, f16* __restrict__ hp, f16* __restrict__ lp, size_t idx) {
  f16 h = (f16)y;
  hp[idx] = h * (f16)64.0f;
  lp[idx] = (f16)((y - (float)h) * 64.0f);
}
__device__ __forceinline__ float join_load(const f16* __restrict__ hp, const f16* __restrict__ lp, size_t idx) {
  return (float)hp[idx] * 0.015625f + (float)lp[idx] * 0.000244140625f;
}

// ---------------------------------------------------------------------------
// 2-TERM split-f16 MFMA GEMM.  acc = Ahi·Bhi + Alo·Bhi = (64a)·(64·f16(b))
//   => y = acc/4096 = a_fp32 · f16(b): activations EXACT, weights rounded to
//   f16 (2^-11 relative weight perturbation — the only numeric change vs the
//   3-term R8/R11 kernel, which was ~a·b + O(2^-11·ab) anyway via hilo).
// A planes [M][K] (lda, hi+lo), B hi plane [N][K] (ldb), C planes [M][ldc].
// 256 thr / 4 waves; BN=128; BK=32; wave-tile (BM/2)x64; MT=BM/32.
// Per wave-iter: 12 ds_read_b128 (was 16), 32 MFMA (was 48); LDS 48KB (was 64).
// LDS swizzle s(row)=(row>>1)&3: conflict-free (R7: SQ_LDS_BANK_CONFLICT=0).
// SHIFT: store col = (n + SHIFT*(m>>6)) & 1023 (scalar path).
// EPI:  y = y_old + tanh(acc/4096).
// ---------------------------------------------------------------------------
template<int BM, bool EPI, int SHIFT>
__global__ __launch_bounds__(256)
void k_gemm16(const f16* __restrict__ Ahi, const f16* __restrict__ Alo, int lda,
              const f16* __restrict__ Bhi, int ldb,
              f16* __restrict__ Chi, f16* __restrict__ Clo, int ldc, int K) {
  constexpr int MT = BM / 32;      // 16-row m-tiles per wave
  constexpr int AI = BM / 64;      // A staging iters (256 chunks each, per plane)
  constexpr int SAE = 2 * 2 * BM * 32;   // f16 elems: [buf][plane][BM*32]
  constexpr int SBE = 2 * 128 * 32;      // f16 elems: [buf][128*32] (hi only)
  __shared__ f16 smem[SAE + SBE];
  auto sAat = [&](int b, int p) -> f16* { return smem + (b * 2 + p) * (BM * 32); };
  auto sBat = [&](int b) -> f16* { return smem + SAE + b * (128 * 32); };

  // XCD-aware swizzle (nwg % 8 == 0 for all our grids)
  const int nwg = gridDim.x * gridDim.y;
  int wg = blockIdx.y * gridDim.x + blockIdx.x;
  wg = (wg & 7) * (nwg >> 3) + (wg >> 3);
  const int bx = wg % gridDim.x, by = wg / gridDim.x;

  const int col0 = bx * 128, row0 = by * BM;
  const int u = threadIdx.x, lane = u & 63, wv = u >> 6;
  const int mh = (wv >> 1) * (BM >> 1);
  const int nh = (wv & 1) * 64;

  unsigned aoff[AI], boff[2];
  unsigned dstA[AI], dstB[2];
#pragma unroll
  for (int i = 0; i < AI; ++i) {
    const int P = i * 256 + u;
    const int row = P >> 2, kc = (P & 3) ^ ((row >> 1) & 3);
    aoff[i] = (unsigned)(row0 + row) * lda + kc * 8;
    dstA[i] = (i * 256 + wv * 64) * 8;
  }
#pragma unroll
  for (int i = 0; i < 2; ++i) {
    const int P = i * 256 + u;
    const int row = P >> 2, kc = (P & 3) ^ ((row >> 1) & 3);
    boff[i] = (unsigned)(col0 + row) * ldb + kc * 8;
    dstB[i] = (i * 256 + wv * 64) * 8;
  }

  const int frag = (lane & 15) * 32 + (((lane >> 4) ^ ((lane >> 1) & 3)) * 8);

  f32x4 acc[MT][4];
#pragma unroll
  for (int i = 0; i < MT; ++i)
#pragma unroll
    for (int j = 0; j < 4; ++j) acc[i][j] = (f32x4){0.f, 0.f, 0.f, 0.f};

  auto stage = [&](int b, int k0) {
#pragma unroll
    for (int i = 0; i < AI; ++i) {
      GLOAD_LDS(Ahi + aoff[i] + k0, sAat(b, 0) + dstA[i]);
      GLOAD_LDS(Alo + aoff[i] + k0, sAat(b, 1) + dstA[i]);
    }
#pragma unroll
    for (int i = 0; i < 2; ++i) {
      GLOAD_LDS(Bhi + boff[i] + k0, sBat(b) + dstB[i]);
    }
  };

  const int niter = K >> 5;
  stage(0, 0);
  __syncthreads();

  int buf = 0;
  for (int it = 0; it < niter; ++it) {
    if (it + 1 < niter) stage(buf ^ 1, (it + 1) << 5);
    f16x8 aH[MT], aL[MT], bH[4];
#pragma unroll
    for (int mt = 0; mt < MT; ++mt) {
      aH[mt] = *(const f16x8*)&sAat(buf, 0)[(mh + mt * 16) * 32 + frag];
      aL[mt] = *(const f16x8*)&sAat(buf, 1)[(mh + mt * 16) * 32 + frag];
    }
#pragma unroll
    for (int nt = 0; nt < 4; ++nt)
      bH[nt] = *(const f16x8*)&sBat(buf)[(nh + nt * 16) * 32 + frag];
#pragma unroll
    for (int mt = 0; mt < MT; ++mt)
#pragma unroll
      for (int nt = 0; nt < 4; ++nt) {
        acc[mt][nt] = __builtin_amdgcn_mfma_f32_16x16x32_f16(aH[mt], bH[nt], acc[mt][nt], 0, 0, 0);
        acc[mt][nt] = __builtin_amdgcn_mfma_f32_16x16x32_f16(aL[mt], bH[nt], acc[mt][nt], 0, 0, 0);
      }
    __syncthreads();
    buf ^= 1;
  }

  if constexpr (SHIFT == 0) {
    // ---- vectorized epilogue: per-wave LDS transpose staging (smem reuse) ----
    f16* eH = smem + wv * (16 * 84 * 2);   // 4 waves x 5376 B = 21.5 KB << smem
    f16* eL = eH + 16 * 84;
    const int lrow4 = (lane >> 4) << 2;
    const int lcol = lane & 15;
#pragma unroll
    for (int mt = 0; mt < MT; ++mt) {
#pragma unroll
      for (int nt = 0; nt < 4; ++nt) {
        const f32x4 a = acc[mt][nt];
#pragma unroll
        for (int r = 0; r < 4; ++r) {
          const float y = a[r] * 0.000244140625f;
          const f16 h = (f16)y;
          const int o = (lrow4 + r) * 84 + nt * 16 + lcol;
          eH[o] = h * (f16)64.0f;
          eL[o] = (f16)((y - (float)h) * 64.0f);
        }
      }
#pragma unroll
      for (int j = 0; j < 2; ++j) {
        const int idx = j * 64 + lane;
        const int row = idx >> 3, ch = idx & 7;
        const f16x8 vh = *(const f16x8*)&eH[row * 84 + ch * 8];
        const f16x8 vl = *(const f16x8*)&eL[row * 84 + ch * 8];
        const int m = row0 + mh + mt * 16 + row;
        const size_t gi = (size_t)m * ldc + col0 + nh + ch * 8;
        if (EPI) {
          const f16x8 oh = *(const f16x8*)&Chi[gi];
          const f16x8 ol = *(const f16x8*)&Clo[gi];
          f16x8 rh, rl;
#pragma unroll
          for (int q = 0; q < 8; ++q) {
            const float yn = (float)vh[q] * 0.015625f + (float)vl[q] * 0.000244140625f;
            const float y  = (float)oh[q] * 0.015625f + (float)ol[q] * 0.000244140625f + tanhf(yn);
            const f16 h = (f16)y;
            rh[q] = h * (f16)64.0f;
            rl[q] = (f16)((y - (float)h) * 64.0f);
          }
          *(f16x8*)&Chi[gi] = rh;
          *(f16x8*)&Clo[gi] = rl;
        } else {
          *(f16x8*)&Chi[gi] = vh;
          *(f16x8*)&Clo[gi] = vl;
        }
      }
    }
  } else {
    // ---- scalar epilogue (rotor shift folded into col index) ----
#pragma unroll
    for (int mt = 0; mt < MT; ++mt)
#pragma unroll
      for (int nt = 0; nt < 4; ++nt) {
        const f32x4 a = acc[mt][nt];
        const int n_base = col0 + nh + nt * 16 + (lane & 15);
#pragma unroll
        for (int r = 0; r < 4; ++r) {
          const int m = row0 + mh + mt * 16 + ((lane >> 4) << 2) + r;
          int n = (n_base + SHIFT * (m >> 6) + 2048) & (DD - 1);
          const size_t idx = (size_t)m * ldc + n;
          float y = a[r] * 0.000244140625f;
          if (EPI) y = join_load(Chi, Clo, idx) + tanhf(y);
          split_store(y, Chi, Clo, idx);
        }
      }
  }
}

// ---------------------------------------------------------------------------
// input projection as 2-term MFMA GEMM:
//   h0_pre[r][j] = sum_k x[b][t][k]*f16(A2)[(j+t)&1023][k] + cvec[(j+t)&1023]
//   (r = t*64+b; t = blockIdx.y uniform since BM=64)
// ---------------------------------------------------------------------------
__global__ __launch_bounds__(256)
void k_in_mfma(const f16* __restrict__ xH, const f16* __restrict__ xL,
               const f16* __restrict__ A2H,
               const float* __restrict__ cvec,
               f16* __restrict__ hH, f16* __restrict__ hL) {
  constexpr int SAE = 2 * 2 * 64 * 32;
  constexpr int SBE = 2 * 128 * 32;
  __shared__ f16 smem[SAE + SBE];
  auto sAat = [&](int b, int p) -> f16* { return smem + (b * 2 + p) * (64 * 32); };
  auto sBat = [&](int b) -> f16* { return smem + SAE + b * (128 * 32); };

  const int bx = blockIdx.x, by = blockIdx.y;   // n-block, m-block(=t)
  const int col0 = bx * 128, row0 = by * 64, t = by;
  const int u = threadIdx.x, lane = u & 63, wv = u >> 6;
  const int mh = (wv >> 1) * 32;
  const int nh = (wv & 1) * 64;

  unsigned aoff, boff[2], dstA, dstB[2];
  {
    const int row = u >> 2, kc = (u & 3) ^ ((row >> 1) & 3);
    aoff = (unsigned)(row * SS + t) * DINN + kc * 8;
    dstA = (unsigned)(wv * 64) * 8;
  }
#pragma unroll
  for (int i = 0; i < 2; ++i) {
    const int P = i * 256 + u;
    const int row = P >> 2, kc = (P & 3) ^ ((row >> 1) & 3);
    const int src = (col0 + row + t) & (DD - 1);
    boff[i] = (unsigned)src * DINN + kc * 8;
    dstB[i] = (i * 256 + wv * 64) * 8;
  }

  const int frag = (lane & 15) * 32 + (((lane >> 4) ^ ((lane >> 1) & 3)) * 8);

  f32x4 acc[2][4];
#pragma unroll
  for (int i = 0; i < 2; ++i)
#pragma unroll
    for (int j = 0; j < 4; ++j) acc[i][j] = (f32x4){0.f, 0.f, 0.f, 0.f};

  auto stage = [&](int b, int k0) {
    GLOAD_LDS(xH + aoff + k0, sAat(b, 0) + dstA);
    GLOAD_LDS(xL + aoff + k0, sAat(b, 1) + dstA);
#pragma unroll
    for (int i = 0; i < 2; ++i)
      GLOAD_LDS(A2H + boff[i] + k0, sBat(b) + dstB[i]);
  };

  stage(0, 0);
  __syncthreads();
  int buf = 0;
#pragma unroll
  for (int it = 0; it < 2; ++it) {
    if (it == 0) stage(1, 32);
    f16x8 aH[2], aL[2], bH[4];
#pragma unroll
    for (int mt = 0; mt < 2; ++mt) {
      aH[mt] = *(const f16x8*)&sAat(buf, 0)[(mh + mt * 16) * 32 + frag];
      aL[mt] = *(const f16x8*)&sAat(buf, 1)[(mh + mt * 16) * 32 + frag];
    }
#pragma unroll
    for (int nt = 0; nt < 4; ++nt)
      bH[nt] = *(const f16x8*)&sBat(buf)[(nh + nt * 16) * 32 + frag];
#pragma unroll
    for (int mt = 0; mt < 2; ++mt)
#pragma unroll
      for (int nt = 0; nt < 4; ++nt) {
        acc[mt][nt] = __builtin_amdgcn_mfma_f32_16x16x32_f16(aH[mt], bH[nt], acc[mt][nt], 0, 0, 0);
        acc[mt][nt] = __builtin_amdgcn_mfma_f32_16x16x32_f16(aL[mt], bH[nt], acc[mt][nt], 0, 0, 0);
      }
    __syncthreads();
    buf ^= 1;
  }

  f16* eH = smem + wv * (16 * 84 * 2);
  f16* eL = eH + 16 * 84;
  const int lrow4 = (lane >> 4) << 2;
  const int lcol = lane & 15;
#pragma unroll
  for (int mt = 0; mt < 2; ++mt) {
#pragma unroll
    for (int nt = 0; nt < 4; ++nt) {
      const f32x4 a = acc[mt][nt];
      const int n = col0 + nh + nt * 16 + lcol;
      const float cv = cvec[(n + t) & (DD - 1)];
#pragma unroll
      for (int r = 0; r < 4; ++r) {
        const float y = a[r] * 0.000244140625f + cv;
        const f16 h = (f16)y;
        const int o = (lrow4 + r) * 84 + nt * 16 + lcol;
        eH[o] = h * (f16)64.0f;
        eL[o] = (f16)((y - (float)h) * 64.0f);
      }
    }
#pragma unroll
    for (int j = 0; j < 2; ++j) {
      const int idx = j * 64 + lane;
      const int row = idx >> 3, ch = idx & 7;
      const f16x8 vh = *(const f16x8*)&eH[row * 84 + ch * 8];
      const f16x8 vl = *(const f16x8*)&eL[row * 84 + ch * 8];
      const int m = row0 + mh + mt * 16 + row;
      const size_t gi = (size_t)m * DD + col0 + nh + ch * 8;
      *(f16x8*)&hH[gi] = vh;
      *(f16x8*)&hL[gi] = vl;
    }
  }
}

// ---------------------------------------------------------------------------
// output projection as 2-term MFMA GEMM: out[b][t][c] = (h @ f16(MoT)^T) + bo
// ---------------------------------------------------------------------------
__global__ __launch_bounds__(256)
void k_out_mfma(const f16* __restrict__ Ahi, const f16* __restrict__ Alo,
                const f16* __restrict__ Bhi,
                const float* __restrict__ bo, float* __restrict__ out) {
  __shared__ f16 sA[2][2][64 * 32];
  __shared__ f16 sB[2][64 * 32];
  const int row0 = blockIdx.x * 64;
  const int u = threadIdx.x, lane = u & 63, wv = u >> 6;
  const int mh = (wv >> 1) * 32, nh = (wv & 1) * 32;

  const int srow = u >> 2, skc = (u & 3) ^ ((srow >> 1) & 3);
  const unsigned aoff = (unsigned)(row0 + srow) * DD + skc * 8;
  const unsigned boff = (unsigned)srow * DD + skc * 8;
  const unsigned dst = (unsigned)(wv * 64) * 8;

  const int frag = (lane & 15) * 32 + (((lane >> 4) ^ ((lane >> 1) & 3)) * 8);

  f32x4 acc[2][2];
#pragma unroll
  for (int i = 0; i < 2; ++i)
#pragma unroll
    for (int j = 0; j < 2; ++j) acc[i][j] = (f32x4){0.f, 0.f, 0.f, 0.f};

  auto stage = [&](int b, int k0) {
    GLOAD_LDS(Ahi + aoff + k0, &sA[b][0][dst]);
    GLOAD_LDS(Alo + aoff + k0, &sA[b][1][dst]);
    GLOAD_LDS(Bhi + boff + k0, &sB[b][dst]);
  };

  stage(0, 0);
  __syncthreads();
  int buf = 0;
  for (int it = 0; it < 32; ++it) {
    if (it + 1 < 32) stage(buf ^ 1, (it + 1) << 5);
    f16x8 aH[2], aL[2], bH[2];
#pragma unroll
    for (int mt = 0; mt < 2; ++mt) {
      aH[mt] = *(const f16x8*)&sA[buf][0][(mh + mt * 16) * 32 + frag];
      aL[mt] = *(const f16x8*)&sA[buf][1][(mh + mt * 16) * 32 + frag];
    }
#pragma unroll
    for (int nt = 0; nt < 2; ++nt)
      bH[nt] = *(const f16x8*)&sB[buf][(nh + nt * 16) * 32 + frag];
#pragma unroll
    for (int mt = 0; mt < 2; ++mt)
#pragma unroll
      for (int nt = 0; nt < 2; ++nt) {
        acc[mt][nt] = __builtin_amdgcn_mfma_f32_16x16x32_f16(aH[mt], bH[nt], acc[mt][nt], 0, 0, 0);
        acc[mt][nt] = __builtin_amdgcn_mfma_f32_16x16x32_f16(aL[mt], bH[nt], acc[mt][nt], 0, 0, 0);
      }
    __syncthreads();
    buf ^= 1;
  }

#pragma unroll
  for (int mt = 0; mt < 2; ++mt)
#pragma unroll
    for (int nt = 0; nt < 2; ++nt) {
      const f32x4 a = acc[mt][nt];
      const int c = nh + nt * 16 + (lane & 15);
      const float bias = bo[c];
#pragma unroll
      for (int r = 0; r < 4; ++r) {
        const int m = row0 + mh + mt * 16 + ((lane >> 4) << 2) + r;
        const int t = m >> 6, b = m & 63;
        out[((size_t)b * SS + t) * DOUTN + c] = a[r] * 0.000244140625f + bias;
      }
    }
}

// ---------------------------------------------------------------------------
// precompute: splits / transposes
// ---------------------------------------------------------------------------
__global__ __launch_bounds__(256)
void k_split(const float* __restrict__ src, f16* __restrict__ hi, f16* __restrict__ lo) {
  const int i = blockIdx.x * 256 + threadIdx.x;
  const float4 v = ((const float4*)src)[i];
  f16x4 h4, l4;
  const float vv[4] = {v.x, v.y, v.z, v.w};
#pragma unroll
  for (int j = 0; j < 4; ++j) {
    f16 h = (f16)vv[j];
    h4[j] = h * (f16)64.0f;
    l4[j] = (f16)((vv[j] - (float)h) * 64.0f);
  }
  ((f16x4*)hi)[i] = h4;
  ((f16x4*)lo)[i] = l4;
}

// transpose + split: src fp32 [dim][dim] (z-batched) -> planes = src^T
__global__ __launch_bounds__(256)
void k_splitT(const float* __restrict__ src, f16* __restrict__ hi, f16* __restrict__ lo, int dim) {
  const size_t zo = (size_t)blockIdx.z * dim * dim;
  src += zo; hi += zo; lo += zo;
  const int i0 = blockIdx.y * 64, j0 = blockIdx.x * 64;
  __shared__ float tb[64][68];
  const int u = threadIdx.x;
#pragma unroll
  for (int it = 0; it < 4; ++it) {
    const int idx = it * 256 + u, rr = idx >> 4, cc = (idx & 15) * 4;
    *(float4*)&tb[rr][cc] = *(const float4*)&src[(size_t)(i0 + rr) * dim + j0 + cc];
  }
  __syncthreads();
#pragma unroll
  for (int it = 0; it < 4; ++it) {
    const int idx = it * 256 + u, rr = idx >> 4, cc = (idx & 15) * 4;
    f16x4 h4, l4;
#pragma unroll
    for (int j = 0; j < 4; ++j) {
      const float y = tb[cc + j][rr];
      f16 h = (f16)y;
      h4[j] = h * (f16)64.0f;
      l4[j] = (f16)((y - (float)h) * 64.0f);
    }
    const size_t o = (size_t)(j0 + rr) * dim + i0 + cc;
    *(f16x4*)&hi[o] = h4;
    *(f16x4*)&lo[o] = l4;
  }
}

// S = R + R^T, split-stored (symmetric => [n][k] fine)
__global__ __launch_bounds__(256)
void k_symm_split(const float* __restrict__ R, f16* __restrict__ hi, f16* __restrict__ lo) {
  const int i0 = blockIdx.y * 64, j0 = blockIdx.x * 64;
  __shared__ float tb[64][68];
  const int u = threadIdx.x;
#pragma unroll
  for (int it = 0; it < 4; ++it) {
    const int idx = it * 256 + u, rr = idx >> 4, cc = (idx & 15) * 4;
    *(float4*)&tb[rr][cc] = *(const float4*)&R[(size_t)(j0 + rr) * DD + i0 + cc];
  }
  __syncthreads();
#pragma unroll
  for (int it = 0; it < 4; ++it) {
    const int idx = it * 256 + u, rr = idx >> 4, cc = (idx & 15) * 4;
    const float4 v = *(const float4*)&R[(size_t)(i0 + rr) * DD + j0 + cc];
    const float vv[4] = {v.x + tb[cc + 0][rr], v.y + tb[cc + 1][rr],
                         v.z + tb[cc + 2][rr], v.w + tb[cc + 3][rr]};
    f16x4 h4, l4;
#pragma unroll
    for (int j = 0; j < 4; ++j) {
      f16 h = (f16)vv[j];
      h4[j] = h * (f16)64.0f;
      l4[j] = (f16)((vv[j] - (float)h) * 64.0f);
    }
    const size_t o = (size_t)(i0 + rr) * DD + j0 + cc;
    *(f16x4*)&hi[o] = h4;
    *(f16x4*)&lo[o] = l4;
  }
}

// f16 plane transpose
__global__ __launch_bounds__(256)
void k_tr16(const f16* __restrict__ in, f16* __restrict__ o, int dim) {
  const int i0 = blockIdx.y * 64, j0 = blockIdx.x * 64;
  __shared__ f16 tb[64][72];
  const int u = threadIdx.x;
#pragma unroll
  for (int it = 0; it < 2; ++it) {
    const int C = it * 256 + u, row = C >> 3, ch = C & 7;
    *(f16x8*)&tb[row][ch * 8] = *(const f16x8*)&in[(size_t)(i0 + row) * dim + j0 + ch * 8];
  }
  __syncthreads();
#pragma unroll
  for (int it = 0; it < 2; ++it) {
    const int C = it * 256 + u, row = C >> 3, ch = C & 7;
    f16x8 v;
#pragma unroll
    for (int j = 0; j < 8; ++j) v[j] = tb[ch * 8 + j][row];
    *(f16x8*)&o[(size_t)(j0 + row) * dim + i0 + ch * 8] = v;
  }
}

// A2 planes = split(P @ Wi)  ([1024][64])
__global__ __launch_bounds__(256)
void k_pwi(const float* __restrict__ P, const float* __restrict__ Wi,
           f16* __restrict__ A2H, f16* __restrict__ A2L) {
  const int m0 = blockIdx.x * 4;
  __shared__ float Ps[4][1024];
  const int u = threadIdx.x;
#pragma unroll
  for (int i = 0; i < 4; ++i) {
    const int idx = i * 256 + u, mi = idx >> 8, kc = (idx & 255) * 4;
    *(float4*)&Ps[mi][kc] = *(const float4*)&P[(size_t)(m0 + mi) * DD + kc];
  }
  __syncthreads();
  const int n = u & 63, mi = u >> 6;
  float acc = 0.f;
  for (int k = 0; k < DD; ++k) acc += Ps[mi][k] * Wi[(size_t)k * DINN + n];
  split_store(acc, A2H, A2L, (size_t)(m0 + mi) * DINN + n);
}

// MoT planes [c][d] = sum_k P[d][k] * Wo[c][k]   (split-stored transposed)
__global__ __launch_bounds__(256)
void k_pwo(const float* __restrict__ P, const float* __restrict__ Wo_,
           f16* __restrict__ MoTH, f16* __restrict__ MoTL) {
  const int d0 = blockIdx.x * 4;
  __shared__ float Ps[4][1024];
  __shared__ float ws[64][65];
  const int u = threadIdx.x;
#pragma unroll
  for (int i = 0; i < 4; ++i) {
    const int idx = i * 256 + u, mi = idx >> 8, kc = (idx & 255) * 4;
    *(float4*)&Ps[mi][kc] = *(const float4*)&P[(size_t)(d0 + mi) * DD + kc];
  }
  const int c = u & 63, di = u >> 6;
  float acc = 0.f;
  for (int k0 = 0; k0 < DD; k0 += 64) {
    __syncthreads();
#pragma unroll
    for (int i = 0; i < 4; ++i) {
      const int idx = i * 256 + u, cc = idx >> 4, kc = (idx & 15) * 4;
      const float4 v = *(const float4*)&Wo_[(size_t)cc * DD + k0 + kc];
      ws[cc][kc] = v.x; ws[cc][kc + 1] = v.y; ws[cc][kc + 2] = v.z; ws[cc][kc + 3] = v.w;
    }
    __syncthreads();
    for (int kk = 0; kk < 64; ++kk) acc += Ps[di][k0 + kk] * ws[c][kk];
  }
  split_store(acc, MoTH, MoTL, (size_t)c * DD + d0 + di);
}

// cvec = P @ bi ; wave per row
__global__ __launch_bounds__(256)
void k_matvec(const float* __restrict__ P, const float* __restrict__ b,
              float* __restrict__ c) {
  const int row = blockIdx.x * 4 + (threadIdx.x >> 6);
  const int l = threadIdx.x & 63;
  float s = 0.f;
  for (int k = l; k < DD; k += 64) s += P[(size_t)row * DD + k] * b[k];
  for (int o = 32; o; o >>= 1) s += __shfl_down(s, o, 64);
  if (l == 0) c[row] = s;
}

// ---------------------------------------------------------------------------
extern "C" void kernel_launch(void* const* d_in, const int* in_sizes, int n_in,
                              void* d_out, int out_size, void* d_ws, size_t ws_size,
                              hipStream_t stream) {
  (void)in_sizes; (void)n_in; (void)out_size; (void)ws_size;
  const float* x    = (const float*)d_in[0];
  const float* Wi   = (const float*)d_in[1];
  const float* bi   = (const float*)d_in[2];
  const float* P    = (const float*)d_in[3];
  const float* rotW = (const float*)d_in[4];
  const float* F    = (const float*)d_in[5];
  const float* G    = (const float*)d_in[6];
  const float* R    = (const float*)d_in[7];
  const float* Wo   = (const float*)d_in[8];
  const float* bo   = (const float*)d_in[9];
  float* out = (float*)d_out;
  char* w = (char*)d_ws;

  constexpr size_t MB = 1u << 20;
  // h planes (f16, [8192][1024], hi scaled x64, lo = resid x64)
  f16* haH = (f16*)(w + 0 * MB);
  f16* haL = (f16*)(w + 16 * MB);
  f16* hbH = (f16*)(w + 32 * MB);
  f16* hbL = (f16*)(w + 48 * MB);
  // weight planes ([n][k] layout)
  f16* B0tH = (f16*)(w + 64 * MB); f16* B0tL = (f16*)(w + 66 * MB);   // W0^T
  f16* B12tH= (f16*)(w + 68 * MB); f16* B12tL= (f16*)(w + 70 * MB);   // W12^T
  f16* BssH = (f16*)(w + 72 * MB); f16* BssL = (f16*)(w + 74 * MB);   // R+R^T
  f16* B12H = (f16*)(w + 76 * MB); f16* B12L = (f16*)(w + 78 * MB);   // W12
  f16* B0H  = (f16*)(w + 80 * MB); f16* B0L  = (f16*)(w + 82 * MB);   // W0
  f16* BFH  = (f16*)(w + 84 * MB); f16* BFL  = (f16*)(w + 85 * MB + 512 * 1024); // F^T x3
  f16* BGH  = (f16*)(w + 87 * MB); f16* BGL  = (f16*)(w + 88 * MB + 512 * 1024); // G^T x3
  // small planes / vectors
  f16* MoTH   = (f16*)(w + 90 * MB);
  f16* MoTL   = (f16*)(w + 90 * MB + 128 * 1024);
  float* cvec = (float*)(w + 90 * MB + 256 * 1024);
  f16* A2H    = (f16*)(w + 91 * MB);
  f16* A2L    = (f16*)(w + 91 * MB + 128 * 1024);
  f16* xsH    = (f16*)(w + 92 * MB);   // split x planes, natural [b][t][k]
  f16* xsL    = (f16*)(w + 93 * MB);
  // temp W1/W2 split planes alias hb region (dead until first GEMM writes hb)
  f16* W1sH = (f16*)(w + 32 * MB); f16* W1sL = (f16*)(w + 34 * MB);
  f16* W2tH = (f16*)(w + 36 * MB); f16* W2tL = (f16*)(w + 38 * MB);

  const float* W0 = rotW;
  const float* W1 = rotW + (1u << 20);
  const float* W2 = rotW + (2u << 20);

  const dim3 blk256(256);
  const size_t FGQ = (size_t)512 * 512;

  // ---- precompute: weight splits ----
  k_split     <<<dim3(1024), blk256, 0, stream>>>(W1, W1sH, W1sL);              // W1 [m][k]
  k_splitT    <<<dim3(16, 16), blk256, 0, stream>>>(W2, W2tH, W2tL, DD);        // W2^T [n][k]
  // W12 = W1 @ f16(W2)
  k_gemm16<64, false, 0><<<dim3(8, 16), blk256, 0, stream>>>(W1sH, W1sL, DD, W2tH, DD, B12H, B12L, DD, DD);
  k_tr16      <<<dim3(16, 16), blk256, 0, stream>>>(B12H, B12tH, DD);           // W12^T hi plane
  k_tr16      <<<dim3(16, 16), blk256, 0, stream>>>(B12L, B12tL, DD);
  k_symm_split<<<dim3(16, 16), blk256, 0, stream>>>(R, BssH, BssL);
  k_splitT    <<<dim3(16, 16), blk256, 0, stream>>>(W0, B0tH, B0tL, DD);        // W0^T
  k_split     <<<dim3(1024), blk256, 0, stream>>>(W0, B0H, B0L);                // W0 as-is
  k_splitT    <<<dim3(8, 8, 3), blk256, 0, stream>>>(F, BFH, BFL, 512);         // F_i^T
  k_splitT    <<<dim3(8, 8, 3), blk256, 0, stream>>>(G, BGH, BGL, 512);         // G_i^T
  k_split     <<<dim3(512), blk256, 0, stream>>>(x, xsH, xsL);                  // x planes
  k_pwi       <<<dim3(256), blk256, 0, stream>>>(P, Wi, A2H, A2L);
  k_pwo       <<<dim3(256), blk256, 0, stream>>>(P, Wo, MoTH, MoTL);
  k_matvec    <<<dim3(256), blk256, 0, stream>>>(P, bi, cvec);

  // ---- main pipeline (all GEMMs 2-term: exact activations x f16 weights) ----
  // input projection (pre-rolled -t via B-row staging)
  k_in_mfma<<<dim3(8, 128), blk256, 0, stream>>>(xsH, xsL, A2H, cvec, haH, haL);

  // rotor 0 fwd (A pre-rolled, store +t)
  k_gemm16<128, false, +1><<<dim3(8, 64), blk256, 0, stream>>>(haH, haL, DD, B0tH, DD, hbH, hbL, DD, DD);
  // rotors 1,2 precomposed
  k_gemm16<128, false, 0><<<dim3(8, 64), blk256, 0, stream>>>(hbH, hbL, DD, B12tH, DD, haH, haL, DD, DD);
  // reversible blocks fwd (in place on ha; h2 = cols 512.., y1 = cols 0..)
  for (int i = 0; i < 3; ++i) {
    k_gemm16<64, true, 0><<<dim3(4, 128), blk256, 0, stream>>>(haH + 512, haL + 512, DD, BFH + i * FGQ, 512, haH, haL, DD, 512);
    k_gemm16<64, true, 0><<<dim3(4, 128), blk256, 0, stream>>>(haH, haL, DD, BGH + i * FGQ, 512, haH + 512, haL + 512, DD, 512);
  }
  // reflector
  k_gemm16<128, false, 0><<<dim3(8, 64), blk256, 0, stream>>>(haH, haL, DD, BssH, DD, hbH, hbL, DD, DD);
  // reversible blocks reversed (in place on hb)
  for (int i = 2; i >= 0; --i) {
    k_gemm16<64, true, 0><<<dim3(4, 128), blk256, 0, stream>>>(hbH + 512, hbL + 512, DD, BFH + i * FGQ, 512, hbH, hbL, DD, 512);
    k_gemm16<64, true, 0><<<dim3(4, 128), blk256, 0, stream>>>(hbH, hbL, DD, BGH + i * FGQ, 512, hbH + 512, hbL + 512, DD, 512);
  }
  // rotors inverse: W12^T-mult (B = W12 as-is), store pre-rolled (-t)
  k_gemm16<128, false, -1><<<dim3(8, 64), blk256, 0, stream>>>(hbH, hbL, DD, B12H, DD, haH, haL, DD, DD);
  // rotor 0 inverse: W0^T-mult (B = W0 as-is), store +t -> linear
  k_gemm16<128, false, +1><<<dim3(8, 64), blk256, 0, stream>>>(haH, haL, DD, B0H, DD, hbH, hbL, DD, DD);

  // output projection
  k_out_mfma<<<dim3(128), blk256, 0, stream>>>(hbH, hbL, MoTH, bo, out);
}

// Round 13
// 419.795 us; speedup vs baseline: 2.0402x; 1.3324x over previous
//
#include <hip/hip_runtime.h>
#include <math.h>

#define DD 1024
#define MM 8192   // B*S rows
#define SS 128
#define DINN 64
#define DOUTN 64

typedef _Float16 f16;
typedef _Float16 f16x8 __attribute__((ext_vector_type(8)));
typedef _Float16 f16x4 __attribute__((ext_vector_type(4)));
typedef float    f32x4 __attribute__((ext_vector_type(4)));

// direct global->LDS, 16B per lane; LDS base must be wave-uniform
#define GLOAD_LDS(g, l) \
  __builtin_amdgcn_global_load_lds((const __attribute__((address_space(1))) void*)(g), \
                                   (__attribute__((address_space(3))) void*)(l), 16, 0, 0)

// ---------------------------------------------------------------------------
// Single-plane f16 MFMA GEMM:  Y = f16(A) @ f16(B)^T-ish, fp32 accumulate.
// Numerics: activations AND weights rounded to f16 (2^-11 relative / stage).
// Justified by R12: the 2^-11 WEIGHT perturbation left absmax at exactly the
// 1-bf16-ulp floor (comparison is in bf16); activation rounding is the same
// magnitude with the same ~neutral propagation (random s=1/sqrt(D) matrices).
// A [M][K] f16 (lda), B [N][K] f16 (ldb), C [M][ldc] f16.
// 256 thr / 4 waves; BN=128; BK=32; wave-tile (BM/2)x64; MT=BM/32.
// Per wave-iter: 8 ds_read_b128, 16 MFMA; LDS 32KB (BM=128).
// LDS swizzle s(row)=(row>>1)&3: conflict-free (R7: SQ_LDS_BANK_CONFLICT=0).
// SHIFT: store col = (n + SHIFT*(m>>6)) & 1023 (scalar path).
// EPI:  y = y_old + tanh(y).
// ---------------------------------------------------------------------------
template<int BM, bool EPI, int SHIFT>
__global__ __launch_bounds__(256)
void k_gemm16(const f16* __restrict__ A, int lda,
              const f16* __restrict__ B, int ldb,
              f16* __restrict__ C, int ldc, int K) {
  constexpr int MT = BM / 32;      // 16-row m-tiles per wave
  constexpr int AI = BM / 64;      // A staging calls per tile
  __shared__ f16 sA[2][BM * 32];
  __shared__ f16 sB[2][128 * 32];

  // XCD-aware swizzle (nwg % 8 == 0 for all our grids)
  const int nwg = gridDim.x * gridDim.y;
  int wg = blockIdx.y * gridDim.x + blockIdx.x;
  wg = (wg & 7) * (nwg >> 3) + (wg >> 3);
  const int bx = wg % gridDim.x, by = wg / gridDim.x;

  const int col0 = bx * 128, row0 = by * BM;
  const int u = threadIdx.x, lane = u & 63, wv = u >> 6;
  const int mh = (wv >> 1) * (BM >> 1);
  const int nh = (wv & 1) * 64;

  unsigned aoff[AI], boff[2];
  unsigned dstA[AI], dstB[2];
#pragma unroll
  for (int i = 0; i < AI; ++i) {
    const int P = i * 256 + u;
    const int row = P >> 2, kc = (P & 3) ^ ((row >> 1) & 3);
    aoff[i] = (unsigned)(row0 + row) * lda + kc * 8;
    dstA[i] = (i * 256 + wv * 64) * 8;
  }
#pragma unroll
  for (int i = 0; i < 2; ++i) {
    const int P = i * 256 + u;
    const int row = P >> 2, kc = (P & 3) ^ ((row >> 1) & 3);
    boff[i] = (unsigned)(col0 + row) * ldb + kc * 8;
    dstB[i] = (i * 256 + wv * 64) * 8;
  }

  const int frag = (lane & 15) * 32 + (((lane >> 4) ^ ((lane >> 1) & 3)) * 8);

  f32x4 acc[MT][4];
#pragma unroll
  for (int i = 0; i < MT; ++i)
#pragma unroll
    for (int j = 0; j < 4; ++j) acc[i][j] = (f32x4){0.f, 0.f, 0.f, 0.f};

  auto stage = [&](int b, int k0) {
#pragma unroll
    for (int i = 0; i < AI; ++i)
      GLOAD_LDS(A + aoff[i] + k0, &sA[b][dstA[i]]);
#pragma unroll
    for (int i = 0; i < 2; ++i)
      GLOAD_LDS(B + boff[i] + k0, &sB[b][dstB[i]]);
  };

  const int niter = K >> 5;
  stage(0, 0);
  __syncthreads();

  int buf = 0;
  for (int it = 0; it < niter; ++it) {
    if (it + 1 < niter) stage(buf ^ 1, (it + 1) << 5);
    f16x8 aF[MT], bF[4];
#pragma unroll
    for (int mt = 0; mt < MT; ++mt)
      aF[mt] = *(const f16x8*)&sA[buf][(mh + mt * 16) * 32 + frag];
#pragma unroll
    for (int nt = 0; nt < 4; ++nt)
      bF[nt] = *(const f16x8*)&sB[buf][(nh + nt * 16) * 32 + frag];
#pragma unroll
    for (int mt = 0; mt < MT; ++mt)
#pragma unroll
      for (int nt = 0; nt < 4; ++nt)
        acc[mt][nt] = __builtin_amdgcn_mfma_f32_16x16x32_f16(aF[mt], bF[nt], acc[mt][nt], 0, 0, 0);
    __syncthreads();
    buf ^= 1;
  }

  if constexpr (SHIFT == 0) {
    // ---- vectorized epilogue: per-wave LDS transpose staging (reuse sB) ----
    f16* eH = &sB[0][0] + wv * (16 * 84);   // 4 x 2688B = 10.75KB <= 16KB
    const int lrow4 = (lane >> 4) << 2;
    const int lcol = lane & 15;
#pragma unroll
    for (int mt = 0; mt < MT; ++mt) {
#pragma unroll
      for (int nt = 0; nt < 4; ++nt) {
        const f32x4 a = acc[mt][nt];
#pragma unroll
        for (int r = 0; r < 4; ++r)
          eH[(lrow4 + r) * 84 + nt * 16 + lcol] = (f16)a[r];
      }
#pragma unroll
      for (int j = 0; j < 2; ++j) {
        const int idx = j * 64 + lane;
        const int row = idx >> 3, ch = idx & 7;
        const f16x8 vh = *(const f16x8*)&eH[row * 84 + ch * 8];
        const int m = row0 + mh + mt * 16 + row;
        const size_t gi = (size_t)m * ldc + col0 + nh + ch * 8;
        if (EPI) {
          const f16x8 oh = *(const f16x8*)&C[gi];
          f16x8 rh;
#pragma unroll
          for (int q = 0; q < 8; ++q)
            rh[q] = (f16)((float)oh[q] + tanhf((float)vh[q]));
          *(f16x8*)&C[gi] = rh;
        } else {
          *(f16x8*)&C[gi] = vh;
        }
      }
    }
  } else {
    // ---- scalar epilogue (rotor shift folded into col index) ----
#pragma unroll
    for (int mt = 0; mt < MT; ++mt)
#pragma unroll
      for (int nt = 0; nt < 4; ++nt) {
        const f32x4 a = acc[mt][nt];
        const int n_base = col0 + nh + nt * 16 + (lane & 15);
#pragma unroll
        for (int r = 0; r < 4; ++r) {
          const int m = row0 + mh + mt * 16 + ((lane >> 4) << 2) + r;
          int n = (n_base + SHIFT * (m >> 6) + 2048) & (DD - 1);
          const size_t idx = (size_t)m * ldc + n;
          float y = a[r];
          if (EPI) y = (float)C[idx] + tanhf(y);
          C[idx] = (f16)y;
        }
      }
  }
}

// ---------------------------------------------------------------------------
// input projection as MFMA GEMM:
//   h0_pre[r][j] = sum_k f16(x)[b][t][k]*f16(A2)[(j+t)&1023][k] + cvec[..]
//   (r = t*64+b; t = blockIdx.y uniform since BM=64)
// ---------------------------------------------------------------------------
__global__ __launch_bounds__(256)
void k_in_mfma(const f16* __restrict__ xS,
               const f16* __restrict__ A2,
               const float* __restrict__ cvec,
               f16* __restrict__ hS) {
  __shared__ f16 sA[2][64 * 32];
  __shared__ f16 sB[2][128 * 32];
  const int bx = blockIdx.x, by = blockIdx.y;   // n-block, m-block(=t)
  const int col0 = bx * 128, row0 = by * 64, t = by;
  const int u = threadIdx.x, lane = u & 63, wv = u >> 6;
  const int mh = (wv >> 1) * 32;
  const int nh = (wv & 1) * 64;

  unsigned aoff, boff[2], dstA, dstB[2];
  {
    const int row = u >> 2, kc = (u & 3) ^ ((row >> 1) & 3);
    aoff = (unsigned)(row * SS + t) * DINN + kc * 8;
    dstA = (unsigned)(wv * 64) * 8;
  }
#pragma unroll
  for (int i = 0; i < 2; ++i) {
    const int P = i * 256 + u;
    const int row = P >> 2, kc = (P & 3) ^ ((row >> 1) & 3);
    const int src = (col0 + row + t) & (DD - 1);
    boff[i] = (unsigned)src * DINN + kc * 8;
    dstB[i] = (i * 256 + wv * 64) * 8;
  }

  const int frag = (lane & 15) * 32 + (((lane >> 4) ^ ((lane >> 1) & 3)) * 8);

  f32x4 acc[2][4];
#pragma unroll
  for (int i = 0; i < 2; ++i)
#pragma unroll
    for (int j = 0; j < 4; ++j) acc[i][j] = (f32x4){0.f, 0.f, 0.f, 0.f};

  auto stage = [&](int b, int k0) {
    GLOAD_LDS(xS + aoff + k0, &sA[b][dstA]);
#pragma unroll
    for (int i = 0; i < 2; ++i)
      GLOAD_LDS(A2 + boff[i] + k0, &sB[b][dstB[i]]);
  };

  stage(0, 0);
  __syncthreads();
  int buf = 0;
#pragma unroll
  for (int it = 0; it < 2; ++it) {
    if (it == 0) stage(1, 32);
    f16x8 aF[2], bF[4];
#pragma unroll
    for (int mt = 0; mt < 2; ++mt)
      aF[mt] = *(const f16x8*)&sA[buf][(mh + mt * 16) * 32 + frag];
#pragma unroll
    for (int nt = 0; nt < 4; ++nt)
      bF[nt] = *(const f16x8*)&sB[buf][(nh + nt * 16) * 32 + frag];
#pragma unroll
    for (int mt = 0; mt < 2; ++mt)
#pragma unroll
      for (int nt = 0; nt < 4; ++nt)
        acc[mt][nt] = __builtin_amdgcn_mfma_f32_16x16x32_f16(aF[mt], bF[nt], acc[mt][nt], 0, 0, 0);
    __syncthreads();
    buf ^= 1;
  }

  f16* eH = &sB[0][0] + wv * (16 * 84);
  const int lrow4 = (lane >> 4) << 2;
  const int lcol = lane & 15;
#pragma unroll
  for (int mt = 0; mt < 2; ++mt) {
#pragma unroll
    for (int nt = 0; nt < 4; ++nt) {
      const f32x4 a = acc[mt][nt];
      const int n = col0 + nh + nt * 16 + lcol;
      const float cv = cvec[(n + t) & (DD - 1)];
#pragma unroll
      for (int r = 0; r < 4; ++r)
        eH[(lrow4 + r) * 84 + nt * 16 + lcol] = (f16)(a[r] + cv);
    }
#pragma unroll
    for (int j = 0; j < 2; ++j) {
      const int idx = j * 64 + lane;
      const int row = idx >> 3, ch = idx & 7;
      const f16x8 vh = *(const f16x8*)&eH[row * 84 + ch * 8];
      const int m = row0 + mh + mt * 16 + row;
      *(f16x8*)&hS[(size_t)m * DD + col0 + nh + ch * 8] = vh;
    }
  }
}

// ---------------------------------------------------------------------------
// output projection as MFMA GEMM: out[b][t][c] = (h @ MoT^T)[r][c] + bo[c]
// ---------------------------------------------------------------------------
__global__ __launch_bounds__(256)
void k_out_mfma(const f16* __restrict__ A,
                const f16* __restrict__ B,
                const float* __restrict__ bo, float* __restrict__ out) {
  __shared__ f16 sA[2][64 * 32];
  __shared__ f16 sB[2][64 * 32];
  const int row0 = blockIdx.x * 64;
  const int u = threadIdx.x, lane = u & 63, wv = u >> 6;
  const int mh = (wv >> 1) * 32, nh = (wv & 1) * 32;

  const int srow = u >> 2, skc = (u & 3) ^ ((srow >> 1) & 3);
  const unsigned aoff = (unsigned)(row0 + srow) * DD + skc * 8;
  const unsigned boff = (unsigned)srow * DD + skc * 8;
  const unsigned dst = (unsigned)(wv * 64) * 8;

  const int frag = (lane & 15) * 32 + (((lane >> 4) ^ ((lane >> 1) & 3)) * 8);

  f32x4 acc[2][2];
#pragma unroll
  for (int i = 0; i < 2; ++i)
#pragma unroll
    for (int j = 0; j < 2; ++j) acc[i][j] = (f32x4){0.f, 0.f, 0.f, 0.f};

  auto stage = [&](int b, int k0) {
    GLOAD_LDS(A + aoff + k0, &sA[b][dst]);
    GLOAD_LDS(B + boff + k0, &sB[b][dst]);
  };

  stage(0, 0);
  __syncthreads();
  int buf = 0;
  for (int it = 0; it < 32; ++it) {
    if (it + 1 < 32) stage(buf ^ 1, (it + 1) << 5);
    f16x8 aF[2], bF[2];
#pragma unroll
    for (int mt = 0; mt < 2; ++mt)
      aF[mt] = *(const f16x8*)&sA[buf][(mh + mt * 16) * 32 + frag];
#pragma unroll
    for (int nt = 0; nt < 2; ++nt)
      bF[nt] = *(const f16x8*)&sB[buf][(nh + nt * 16) * 32 + frag];
#pragma unroll
    for (int mt = 0; mt < 2; ++mt)
#pragma unroll
      for (int nt = 0; nt < 2; ++nt)
        acc[mt][nt] = __builtin_amdgcn_mfma_f32_16x16x32_f16(aF[mt], bF[nt], acc[mt][nt], 0, 0, 0);
    __syncthreads();
    buf ^= 1;
  }

#pragma unroll
  for (int mt = 0; mt < 2; ++mt)
#pragma unroll
    for (int nt = 0; nt < 2; ++nt) {
      const f32x4 a = acc[mt][nt];
      const int c = nh + nt * 16 + (lane & 15);
      const float bias = bo[c];
#pragma unroll
      for (int r = 0; r < 4; ++r) {
        const int m = row0 + mh + mt * 16 + ((lane >> 4) << 2) + r;
        const int t = m >> 6, b = m & 63;
        out[((size_t)b * SS + t) * DOUTN + c] = a[r] + bias;
      }
    }
}

// ---------------------------------------------------------------------------
// precompute: f32 -> f16 casts / transposes
// ---------------------------------------------------------------------------
__global__ __launch_bounds__(256)
void k_cvt(const float* __restrict__ src, f16* __restrict__ dst) {
  const int i = blockIdx.x * 256 + threadIdx.x;
  const float4 v = ((const float4*)src)[i];
  f16x4 h4;
  h4[0] = (f16)v.x; h4[1] = (f16)v.y; h4[2] = (f16)v.z; h4[3] = (f16)v.w;
  ((f16x4*)dst)[i] = h4;
}

// transpose + cast: src fp32 [dim][dim] (z-batched) -> dst f16 = src^T
__global__ __launch_bounds__(256)
void k_cvtT(const float* __restrict__ src, f16* __restrict__ dst, int dim) {
  src += (size_t)blockIdx.z * dim * dim;
  dst += (size_t)blockIdx.z * dim * dim;
  const int i0 = blockIdx.y * 64, j0 = blockIdx.x * 64;
  __shared__ float tb[64][68];
  const int u = threadIdx.x;
#pragma unroll
  for (int it = 0; it < 4; ++it) {
    const int idx = it * 256 + u, rr = idx >> 4, cc = (idx & 15) * 4;
    *(float4*)&tb[rr][cc] = *(const float4*)&src[(size_t)(i0 + rr) * dim + j0 + cc];
  }
  __syncthreads();
#pragma unroll
  for (int it = 0; it < 4; ++it) {
    const int idx = it * 256 + u, rr = idx >> 4, cc = (idx & 15) * 4;
    f16x4 h4;
#pragma unroll
    for (int j = 0; j < 4; ++j) h4[j] = (f16)tb[cc + j][rr];
    *(f16x4*)&dst[(size_t)(j0 + rr) * dim + i0 + cc] = h4;
  }
}

// S = R + R^T, cast f16 (symmetric => [n][k] fine)
__global__ __launch_bounds__(256)
void k_symm_cvt(const float* __restrict__ R, f16* __restrict__ S) {
  const int i0 = blockIdx.y * 64, j0 = blockIdx.x * 64;
  __shared__ float tb[64][68];
  const int u = threadIdx.x;
#pragma unroll
  for (int it = 0; it < 4; ++it) {
    const int idx = it * 256 + u, rr = idx >> 4, cc = (idx & 15) * 4;
    *(float4*)&tb[rr][cc] = *(const float4*)&R[(size_t)(j0 + rr) * DD + i0 + cc];
  }
  __syncthreads();
#pragma unroll
  for (int it = 0; it < 4; ++it) {
    const int idx = it * 256 + u, rr = idx >> 4, cc = (idx & 15) * 4;
    const float4 v = *(const float4*)&R[(size_t)(i0 + rr) * DD + j0 + cc];
    f16x4 h4;
    h4[0] = (f16)(v.x + tb[cc + 0][rr]); h4[1] = (f16)(v.y + tb[cc + 1][rr]);
    h4[2] = (f16)(v.z + tb[cc + 2][rr]); h4[3] = (f16)(v.w + tb[cc + 3][rr]);
    *(f16x4*)&S[(size_t)(i0 + rr) * DD + j0 + cc] = h4;
  }
}

// f16 plane transpose
__global__ __launch_bounds__(256)
void k_tr16(const f16* __restrict__ in, f16* __restrict__ o, int dim) {
  const int i0 = blockIdx.y * 64, j0 = blockIdx.x * 64;
  __shared__ f16 tb[64][72];
  const int u = threadIdx.x;
#pragma unroll
  for (int it = 0; it < 2; ++it) {
    const int C = it * 256 + u, row = C >> 3, ch = C & 7;
    *(f16x8*)&tb[row][ch * 8] = *(const f16x8*)&in[(size_t)(i0 + row) * dim + j0 + ch * 8];
  }
  __syncthreads();
#pragma unroll
  for (int it = 0; it < 2; ++it) {
    const int C = it * 256 + u, row = C >> 3, ch = C & 7;
    f16x8 v;
#pragma unroll
    for (int j = 0; j < 8; ++j) v[j] = tb[ch * 8 + j][row];
    *(f16x8*)&o[(size_t)(j0 + row) * dim + i0 + ch * 8] = v;
  }
}

// A2 = f16(P @ Wi)  ([1024][64])
__global__ __launch_bounds__(256)
void k_pwi(const float* __restrict__ P, const float* __restrict__ Wi,
           f16* __restrict__ A2) {
  const int m0 = blockIdx.x * 4;
  __shared__ float Ps[4][1024];
  const int u = threadIdx.x;
#pragma unroll
  for (int i = 0; i < 4; ++i) {
    const int idx = i * 256 + u, mi = idx >> 8, kc = (idx & 255) * 4;
    *(float4*)&Ps[mi][kc] = *(const float4*)&P[(size_t)(m0 + mi) * DD + kc];
  }
  __syncthreads();
  const int n = u & 63, mi = u >> 6;
  float acc = 0.f;
  for (int k = 0; k < DD; ++k) acc += Ps[mi][k] * Wi[(size_t)k * DINN + n];
  A2[(size_t)(m0 + mi) * DINN + n] = (f16)acc;
}

// MoT [c][d] = f16(sum_k P[d][k] * Wo[c][k])
__global__ __launch_bounds__(256)
void k_pwo(const float* __restrict__ P, const float* __restrict__ Wo_,
           f16* __restrict__ MoT) {
  const int d0 = blockIdx.x * 4;
  __shared__ float Ps[4][1024];
  __shared__ float ws[64][65];
  const int u = threadIdx.x;
#pragma unroll
  for (int i = 0; i < 4; ++i) {
    const int idx = i * 256 + u, mi = idx >> 8, kc = (idx & 255) * 4;
    *(float4*)&Ps[mi][kc] = *(const float4*)&P[(size_t)(d0 + mi) * DD + kc];
  }
  const int c = u & 63, di = u >> 6;
  float acc = 0.f;
  for (int k0 = 0; k0 < DD; k0 += 64) {
    __syncthreads();
#pragma unroll
    for (int i = 0; i < 4; ++i) {
      const int idx = i * 256 + u, cc = idx >> 4, kc = (idx & 15) * 4;
      const float4 v = *(const float4*)&Wo_[(size_t)cc * DD + k0 + kc];
      ws[cc][kc] = v.x; ws[cc][kc + 1] = v.y; ws[cc][kc + 2] = v.z; ws[cc][kc + 3] = v.w;
    }
    __syncthreads();
    for (int kk = 0; kk < 64; ++kk) acc += Ps[di][k0 + kk] * ws[c][kk];
  }
  MoT[(size_t)c * DD + d0 + di] = (f16)acc;
}

// cvec = P @ bi ; wave per row
__global__ __launch_bounds__(256)
void k_matvec(const float* __restrict__ P, const float* __restrict__ b,
              float* __restrict__ c) {
  const int row = blockIdx.x * 4 + (threadIdx.x >> 6);
  const int l = threadIdx.x & 63;
  float s = 0.f;
  for (int k = l; k < DD; k += 64) s += P[(size_t)row * DD + k] * b[k];
  for (int o = 32; o; o >>= 1) s += __shfl_down(s, o, 64);
  if (l == 0) c[row] = s;
}

// ---------------------------------------------------------------------------
extern "C" void kernel_launch(void* const* d_in, const int* in_sizes, int n_in,
                              void* d_out, int out_size, void* d_ws, size_t ws_size,
                              hipStream_t stream) {
  (void)in_sizes; (void)n_in; (void)out_size; (void)ws_size;
  const float* x    = (const float*)d_in[0];
  const float* Wi   = (const float*)d_in[1];
  const float* bi   = (const float*)d_in[2];
  const float* P    = (const float*)d_in[3];
  const float* rotW = (const float*)d_in[4];
  const float* F    = (const float*)d_in[5];
  const float* G    = (const float*)d_in[6];
  const float* R    = (const float*)d_in[7];
  const float* Wo   = (const float*)d_in[8];
  const float* bo   = (const float*)d_in[9];
  float* out = (float*)d_out;
  char* w = (char*)d_ws;

  constexpr size_t MB = 1u << 20;
  // h planes (f16, [8192][1024], single plane)
  f16* haS = (f16*)(w + 0 * MB);       // 16MB
  f16* hbS = (f16*)(w + 16 * MB);      // 16MB
  // weight planes ([n][k] layout), 2MB each
  f16* B0t = (f16*)(w + 32 * MB);      // W0^T
  f16* B12t= (f16*)(w + 34 * MB);      // W12^T
  f16* Bss = (f16*)(w + 36 * MB);      // R+R^T
  f16* B12 = (f16*)(w + 38 * MB);      // W12
  f16* B0  = (f16*)(w + 40 * MB);      // W0
  f16* BF  = (f16*)(w + 42 * MB);      // F^T x3 (1.5MB)
  f16* BG  = (f16*)(w + 44 * MB);      // G^T x3 (1.5MB)
  // small planes / vectors
  f16* MoT    = (f16*)(w + 46 * MB);             // 128KB
  f16* A2     = (f16*)(w + 46 * MB + 128 * 1024);
  float* cvec = (float*)(w + 46 * MB + 256 * 1024);
  f16* xs     = (f16*)(w + 47 * MB);             // 1MB: f16(x), natural layout
  // temps
  f16* W1s = (f16*)(w + 48 * MB);      // 2MB
  f16* W2t = (f16*)(w + 50 * MB);      // 2MB

  const float* W0 = rotW;
  const float* W1 = rotW + (1u << 20);
  const float* W2 = rotW + (2u << 20);

  const dim3 blk256(256);
  const size_t FGQ = (size_t)512 * 512;

  // ---- precompute: weight casts ----
  k_cvt     <<<dim3(1024), blk256, 0, stream>>>(W1, W1s);                 // W1 [m][k]
  k_cvtT    <<<dim3(16, 16), blk256, 0, stream>>>(W2, W2t, DD);           // W2^T [n][k]
  // W12 = f16(W1) @ f16(W2)
  k_gemm16<64, false, 0><<<dim3(8, 16), blk256, 0, stream>>>(W1s, DD, W2t, DD, B12, DD, DD);
  k_tr16    <<<dim3(16, 16), blk256, 0, stream>>>(B12, B12t, DD);         // W12^T
  k_symm_cvt<<<dim3(16, 16), blk256, 0, stream>>>(R, Bss);
  k_cvtT    <<<dim3(16, 16), blk256, 0, stream>>>(W0, B0t, DD);           // W0^T
  k_cvt     <<<dim3(1024), blk256, 0, stream>>>(W0, B0);                  // W0 as-is
  k_cvtT    <<<dim3(8, 8, 3), blk256, 0, stream>>>(F, BF, 512);           // F_i^T
  k_cvtT    <<<dim3(8, 8, 3), blk256, 0, stream>>>(G, BG, 512);           // G_i^T
  k_cvt     <<<dim3(512), blk256, 0, stream>>>(x, xs);                    // x f16
  k_pwi     <<<dim3(256), blk256, 0, stream>>>(P, Wi, A2);
  k_pwo     <<<dim3(256), blk256, 0, stream>>>(P, Wo, MoT);
  k_matvec  <<<dim3(256), blk256, 0, stream>>>(P, bi, cvec);

  // ---- main pipeline (single-plane f16 activations, fp32 MFMA accum) ----
  // input projection (pre-rolled -t via B-row staging)
  k_in_mfma<<<dim3(8, 128), blk256, 0, stream>>>(xs, A2, cvec, haS);

  // rotor 0 fwd (A pre-rolled, store +t)
  k_gemm16<128, false, +1><<<dim3(8, 64), blk256, 0, stream>>>(haS, DD, B0t, DD, hbS, DD, DD);
  // rotors 1,2 precomposed
  k_gemm16<128, false, 0><<<dim3(8, 64), blk256, 0, stream>>>(hbS, DD, B12t, DD, haS, DD, DD);
  // reversible blocks fwd (in place on ha; h2 = cols 512.., y1 = cols 0..)
  for (int i = 0; i < 3; ++i) {
    k_gemm16<64, true, 0><<<dim3(4, 128), blk256, 0, stream>>>(haS + 512, DD, BF + i * FGQ, 512, haS, DD, 512);
    k_gemm16<64, true, 0><<<dim3(4, 128), blk256, 0, stream>>>(haS, DD, BG + i * FGQ, 512, haS + 512, DD, 512);
  }
  // reflector
  k_gemm16<128, false, 0><<<dim3(8, 64), blk256, 0, stream>>>(haS, DD, Bss, DD, hbS, DD, DD);
  // reversible blocks reversed (in place on hb)
  for (int i = 2; i >= 0; --i) {
    k_gemm16<64, true, 0><<<dim3(4, 128), blk256, 0, stream>>>(hbS + 512, DD, BF + i * FGQ, 512, hbS, DD, 512);
    k_gemm16<64, true, 0><<<dim3(4, 128), blk256, 0, stream>>>(hbS, DD, BG + i * FGQ, 512, hbS + 512, DD, 512);
  }
  // rotors inverse: W12^T-mult (B = W12 as-is), store pre-rolled (-t)
  k_gemm16<128, false, -1><<<dim3(8, 64), blk256, 0, stream>>>(hbS, DD, B12, DD, haS, DD, DD);
  // rotor 0 inverse: W0^T-mult (B = W0 as-is), store +t -> linear
  k_gemm16<128, false, +1><<<dim3(8, 64), blk256, 0, stream>>>(haS, DD, B0, DD, hbS, DD, DD);

  // output projection
  k_out_mfma<<<dim3(128), blk256, 0, stream>>>(hbS, MoT, bo, out);
}

// Round 15
// 401.303 us; speedup vs baseline: 2.1342x; 1.0461x over previous
//
#include <hip/hip_runtime.h>
#include <math.h>

#define DD 1024
#define MM 8192   // B*S rows
#define SS 128
#define DINN 64
#define DOUTN 64

typedef _Float16 f16;
typedef _Float16 f16x8 __attribute__((ext_vector_type(8)));
typedef _Float16 f16x4 __attribute__((ext_vector_type(4)));
typedef float    f32x4 __attribute__((ext_vector_type(4)));

// direct global->LDS, 16B per lane; LDS base must be wave-uniform
#define GLOAD_LDS(g, l) \
  __builtin_amdgcn_global_load_lds((const __attribute__((address_space(1))) void*)(g), \
                                   (__attribute__((address_space(3))) void*)(l), 16, 0, 0)

// ---------------------------------------------------------------------------
// Single-plane f16 MFMA GEMM (R13-validated numerics: f16 activations+weights,
// fp32 accum; absmax stayed at the 1-bf16-ulp floor).
// A [M][K] f16 (lda), B [N][K] f16 (ldb), C [M][ldc] f16.
// 256 thr / 4 waves; BN=128; BK=32; wave-tile (BM/2)x64; MT=BM/32.
// R14: fulls now BM=64 grid 1024 (4 blocks/CU vs 2) — trades read-ratio
// (2.0 -> 1.33) for 2x TLP to hide the 2-phase stage/barrier serialization.
// LDS swizzle s(row)=(row>>1)&3: conflict-free (R7: SQ_LDS_BANK_CONFLICT=0).
// SHIFT: store col = (n + SHIFT*(m>>6)) & 1023 (scalar path).
// EPI:  y = y_old + tanh(y).
// ---------------------------------------------------------------------------
template<int BM, bool EPI, int SHIFT>
__global__ __launch_bounds__(256)
void k_gemm16(const f16* __restrict__ A, int lda,
              const f16* __restrict__ B, int ldb,
              f16* __restrict__ C, int ldc, int K) {
  constexpr int MT = BM / 32;      // 16-row m-tiles per wave
  constexpr int AI = BM / 64;      // A staging calls per tile
  __shared__ f16 sA[2][BM * 32];
  __shared__ f16 sB[2][128 * 32];

  // XCD-aware swizzle (nwg % 8 == 0 for all our grids)
  const int nwg = gridDim.x * gridDim.y;
  int wg = blockIdx.y * gridDim.x + blockIdx.x;
  wg = (wg & 7) * (nwg >> 3) + (wg >> 3);
  const int bx = wg % gridDim.x, by = wg / gridDim.x;

  const int col0 = bx * 128, row0 = by * BM;
  const int u = threadIdx.x, lane = u & 63, wv = u >> 6;
  const int mh = (wv >> 1) * (BM >> 1);
  const int nh = (wv & 1) * 64;

  unsigned aoff[AI], boff[2];
  unsigned dstA[AI], dstB[2];
#pragma unroll
  for (int i = 0; i < AI; ++i) {
    const int P = i * 256 + u;
    const int row = P >> 2, kc = (P & 3) ^ ((row >> 1) & 3);
    aoff[i] = (unsigned)(row0 + row) * lda + kc * 8;
    dstA[i] = (i * 256 + wv * 64) * 8;
  }
#pragma unroll
  for (int i = 0; i < 2; ++i) {
    const int P = i * 256 + u;
    const int row = P >> 2, kc = (P & 3) ^ ((row >> 1) & 3);
    boff[i] = (unsigned)(col0 + row) * ldb + kc * 8;
    dstB[i] = (i * 256 + wv * 64) * 8;
  }

  const int frag = (lane & 15) * 32 + (((lane >> 4) ^ ((lane >> 1) & 3)) * 8);

  f32x4 acc[MT][4];
#pragma unroll
  for (int i = 0; i < MT; ++i)
#pragma unroll
    for (int j = 0; j < 4; ++j) acc[i][j] = (f32x4){0.f, 0.f, 0.f, 0.f};

  auto stage = [&](int b, int k0) {
#pragma unroll
    for (int i = 0; i < AI; ++i)
      GLOAD_LDS(A + aoff[i] + k0, &sA[b][dstA[i]]);
#pragma unroll
    for (int i = 0; i < 2; ++i)
      GLOAD_LDS(B + boff[i] + k0, &sB[b][dstB[i]]);
  };

  const int niter = K >> 5;
  stage(0, 0);
  __syncthreads();

  int buf = 0;
  for (int it = 0; it < niter; ++it) {
    if (it + 1 < niter) stage(buf ^ 1, (it + 1) << 5);
    f16x8 aF[MT], bF[4];
#pragma unroll
    for (int mt = 0; mt < MT; ++mt)
      aF[mt] = *(const f16x8*)&sA[buf][(mh + mt * 16) * 32 + frag];
#pragma unroll
    for (int nt = 0; nt < 4; ++nt)
      bF[nt] = *(const f16x8*)&sB[buf][(nh + nt * 16) * 32 + frag];
#pragma unroll
    for (int mt = 0; mt < MT; ++mt)
#pragma unroll
      for (int nt = 0; nt < 4; ++nt)
        acc[mt][nt] = __builtin_amdgcn_mfma_f32_16x16x32_f16(aF[mt], bF[nt], acc[mt][nt], 0, 0, 0);
    __syncthreads();
    buf ^= 1;
  }

  if constexpr (SHIFT == 0) {
    // ---- vectorized epilogue: per-wave LDS transpose staging (reuse sB) ----
    f16* eH = &sB[0][0] + wv * (16 * 84);
    const int lrow4 = (lane >> 4) << 2;
    const int lcol = lane & 15;
#pragma unroll
    for (int mt = 0; mt < MT; ++mt) {
#pragma unroll
      for (int nt = 0; nt < 4; ++nt) {
        const f32x4 a = acc[mt][nt];
#pragma unroll
        for (int r = 0; r < 4; ++r)
          eH[(lrow4 + r) * 84 + nt * 16 + lcol] = (f16)a[r];
      }
#pragma unroll
      for (int j = 0; j < 2; ++j) {
        const int idx = j * 64 + lane;
        const int row = idx >> 3, ch = idx & 7;
        const f16x8 vh = *(const f16x8*)&eH[row * 84 + ch * 8];
        const int m = row0 + mh + mt * 16 + row;
        const size_t gi = (size_t)m * ldc + col0 + nh + ch * 8;
        if (EPI) {
          const f16x8 oh = *(const f16x8*)&C[gi];
          f16x8 rh;
#pragma unroll
          for (int q = 0; q < 8; ++q)
            rh[q] = (f16)((float)oh[q] + tanhf((float)vh[q]));
          *(f16x8*)&C[gi] = rh;
        } else {
          *(f16x8*)&C[gi] = vh;
        }
      }
    }
  } else {
    // ---- scalar epilogue (rotor shift folded into col index) ----
#pragma unroll
    for (int mt = 0; mt < MT; ++mt)
#pragma unroll
      for (int nt = 0; nt < 4; ++nt) {
        const f32x4 a = acc[mt][nt];
        const int n_base = col0 + nh + nt * 16 + (lane & 15);
#pragma unroll
        for (int r = 0; r < 4; ++r) {
          const int m = row0 + mh + mt * 16 + ((lane >> 4) << 2) + r;
          int n = (n_base + SHIFT * (m >> 6) + 2048) & (DD - 1);
          const size_t idx = (size_t)m * ldc + n;
          float y = a[r];
          if (EPI) y = (float)C[idx] + tanhf(y);
          C[idx] = (f16)y;
        }
      }
  }
}

// ---------------------------------------------------------------------------
// W12 split-K partials: z-slice of K (256 each), fp32 partial out.
// grid (8,16,4), BM=64/BN=128, same staging/swizzle as k_gemm16.
// ---------------------------------------------------------------------------
__global__ __launch_bounds__(256)
void k_w12part(const f16* __restrict__ A, const f16* __restrict__ B,
               float* __restrict__ Cp) {
  __shared__ f16 sA[2][64 * 32];
  __shared__ f16 sB[2][128 * 32];
  const int kOff = blockIdx.z * 256;
  float* Co = Cp + (size_t)blockIdx.z * DD * DD;
  const int col0 = blockIdx.x * 128, row0 = blockIdx.y * 64;
  const int u = threadIdx.x, lane = u & 63, wv = u >> 6;
  const int mh = (wv >> 1) * 32, nh = (wv & 1) * 64;

  unsigned aoff, boff[2], dstA, dstB[2];
  {
    const int row = u >> 2, kc = (u & 3) ^ ((row >> 1) & 3);
    aoff = (unsigned)(row0 + row) * DD + kOff + kc * 8;
    dstA = (unsigned)(wv * 64) * 8;
  }
#pragma unroll
  for (int i = 0; i < 2; ++i) {
    const int P = i * 256 + u;
    const int row = P >> 2, kc = (P & 3) ^ ((row >> 1) & 3);
    boff[i] = (unsigned)(col0 + row) * DD + kOff + kc * 8;
    dstB[i] = (i * 256 + wv * 64) * 8;
  }
  const int frag = (lane & 15) * 32 + (((lane >> 4) ^ ((lane >> 1) & 3)) * 8);

  f32x4 acc[2][4];
#pragma unroll
  for (int i = 0; i < 2; ++i)
#pragma unroll
    for (int j = 0; j < 4; ++j) acc[i][j] = (f32x4){0.f, 0.f, 0.f, 0.f};

  auto stage = [&](int b, int k0) {
    GLOAD_LDS(A + aoff + k0, &sA[b][dstA]);
#pragma unroll
    for (int i = 0; i < 2; ++i)
      GLOAD_LDS(B + boff[i] + k0, &sB[b][dstB[i]]);
  };

  stage(0, 0);
  __syncthreads();
  int buf = 0;
  for (int it = 0; it < 8; ++it) {
    if (it + 1 < 8) stage(buf ^ 1, (it + 1) << 5);
    f16x8 aF[2], bF[4];
#pragma unroll
    for (int mt = 0; mt < 2; ++mt)
      aF[mt] = *(const f16x8*)&sA[buf][(mh + mt * 16) * 32 + frag];
#pragma unroll
    for (int nt = 0; nt < 4; ++nt)
      bF[nt] = *(const f16x8*)&sB[buf][(nh + nt * 16) * 32 + frag];
#pragma unroll
    for (int mt = 0; mt < 2; ++mt)
#pragma unroll
      for (int nt = 0; nt < 4; ++nt)
        acc[mt][nt] = __builtin_amdgcn_mfma_f32_16x16x32_f16(aF[mt], bF[nt], acc[mt][nt], 0, 0, 0);
    __syncthreads();
    buf ^= 1;
  }
#pragma unroll
  for (int mt = 0; mt < 2; ++mt)
#pragma unroll
    for (int nt = 0; nt < 4; ++nt) {
      const f32x4 a = acc[mt][nt];
      const int n = col0 + nh + nt * 16 + (lane & 15);
#pragma unroll
      for (int r = 0; r < 4; ++r) {
        const int m = row0 + mh + mt * 16 + ((lane >> 4) << 2) + r;
        Co[(size_t)m * DD + n] = a[r];
      }
    }
}

// B12 = f16(sum of 4 fp32 partials)
__global__ __launch_bounds__(256)
void k_sum4(const float* __restrict__ Wp, f16* __restrict__ B12) {
  const int i = blockIdx.x * 256 + threadIdx.x;
  const float4 s0 = ((const float4*)Wp)[i];
  const float4 s1 = ((const float4*)(Wp + (1u << 20)))[i];
  const float4 s2 = ((const float4*)(Wp + (2u << 20)))[i];
  const float4 s3 = ((const float4*)(Wp + (3u << 20)))[i];
  f16x4 h4;
  h4[0] = (f16)(s0.x + s1.x + s2.x + s3.x);
  h4[1] = (f16)(s0.y + s1.y + s2.y + s3.y);
  h4[2] = (f16)(s0.z + s1.z + s2.z + s3.z);
  h4[3] = (f16)(s0.w + s1.w + s2.w + s3.w);
  ((f16x4*)B12)[i] = h4;
}

// ---------------------------------------------------------------------------
// input projection as MFMA GEMM (pre-rolled -t via B-row staging)
// ---------------------------------------------------------------------------
__global__ __launch_bounds__(256)
void k_in_mfma(const f16* __restrict__ xS,
               const f16* __restrict__ A2,
               const float* __restrict__ cvec,
               f16* __restrict__ hS) {
  __shared__ f16 sA[2][64 * 32];
  __shared__ f16 sB[2][128 * 32];
  const int bx = blockIdx.x, by = blockIdx.y;   // n-block, m-block(=t)
  const int col0 = bx * 128, row0 = by * 64, t = by;
  const int u = threadIdx.x, lane = u & 63, wv = u >> 6;
  const int mh = (wv >> 1) * 32;
  const int nh = (wv & 1) * 64;

  unsigned aoff, boff[2], dstA, dstB[2];
  {
    const int row = u >> 2, kc = (u & 3) ^ ((row >> 1) & 3);
    aoff = (unsigned)(row * SS + t) * DINN + kc * 8;
    dstA = (unsigned)(wv * 64) * 8;
  }
#pragma unroll
  for (int i = 0; i < 2; ++i) {
    const int P = i * 256 + u;
    const int row = P >> 2, kc = (P & 3) ^ ((row >> 1) & 3);
    const int src = (col0 + row + t) & (DD - 1);
    boff[i] = (unsigned)src * DINN + kc * 8;
    dstB[i] = (i * 256 + wv * 64) * 8;
  }

  const int frag = (lane & 15) * 32 + (((lane >> 4) ^ ((lane >> 1) & 3)) * 8);

  f32x4 acc[2][4];
#pragma unroll
  for (int i = 0; i < 2; ++i)
#pragma unroll
    for (int j = 0; j < 4; ++j) acc[i][j] = (f32x4){0.f, 0.f, 0.f, 0.f};

  auto stage = [&](int b, int k0) {
    GLOAD_LDS(xS + aoff + k0, &sA[b][dstA]);
#pragma unroll
    for (int i = 0; i < 2; ++i)
      GLOAD_LDS(A2 + boff[i] + k0, &sB[b][dstB[i]]);
  };

  stage(0, 0);
  __syncthreads();
  int buf = 0;
#pragma unroll
  for (int it = 0; it < 2; ++it) {
    if (it == 0) stage(1, 32);
    f16x8 aF[2], bF[4];
#pragma unroll
    for (int mt = 0; mt < 2; ++mt)
      aF[mt] = *(const f16x8*)&sA[buf][(mh + mt * 16) * 32 + frag];
#pragma unroll
    for (int nt = 0; nt < 4; ++nt)
      bF[nt] = *(const f16x8*)&sB[buf][(nh + nt * 16) * 32 + frag];
#pragma unroll
    for (int mt = 0; mt < 2; ++mt)
#pragma unroll
      for (int nt = 0; nt < 4; ++nt)
        acc[mt][nt] = __builtin_amdgcn_mfma_f32_16x16x32_f16(aF[mt], bF[nt], acc[mt][nt], 0, 0, 0);
    __syncthreads();
    buf ^= 1;
  }

  f16* eH = &sB[0][0] + wv * (16 * 84);
  const int lrow4 = (lane >> 4) << 2;
  const int lcol = lane & 15;
#pragma unroll
  for (int mt = 0; mt < 2; ++mt) {
#pragma unroll
    for (int nt = 0; nt < 4; ++nt) {
      const f32x4 a = acc[mt][nt];
      const int n = col0 + nh + nt * 16 + lcol;
      const float cv = cvec[(n + t) & (DD - 1)];
#pragma unroll
      for (int r = 0; r < 4; ++r)
        eH[(lrow4 + r) * 84 + nt * 16 + lcol] = (f16)(a[r] + cv);
    }
#pragma unroll
    for (int j = 0; j < 2; ++j) {
      const int idx = j * 64 + lane;
      const int row = idx >> 3, ch = idx & 7;
      const f16x8 vh = *(const f16x8*)&eH[row * 84 + ch * 8];
      const int m = row0 + mh + mt * 16 + row;
      *(f16x8*)&hS[(size_t)m * DD + col0 + nh + ch * 8] = vh;
    }
  }
}

// ---------------------------------------------------------------------------
// output projection as MFMA GEMM: out[b][t][c] = (h @ MoT^T)[r][c] + bo[c]
// ---------------------------------------------------------------------------
__global__ __launch_bounds__(256)
void k_out_mfma(const f16* __restrict__ A,
                const f16* __restrict__ B,
                const float* __restrict__ bo, float* __restrict__ out) {
  __shared__ f16 sA[2][64 * 32];
  __shared__ f16 sB[2][64 * 32];
  const int row0 = blockIdx.x * 64;
  const int u = threadIdx.x, lane = u & 63, wv = u >> 6;
  const int mh = (wv >> 1) * 32, nh = (wv & 1) * 32;

  const int srow = u >> 2, skc = (u & 3) ^ ((srow >> 1) & 3);
  const unsigned aoff = (unsigned)(row0 + srow) * DD + skc * 8;
  const unsigned boff = (unsigned)srow * DD + skc * 8;
  const unsigned dst = (unsigned)(wv * 64) * 8;

  const int frag = (lane & 15) * 32 + (((lane >> 4) ^ ((lane >> 1) & 3)) * 8);

  f32x4 acc[2][2];
#pragma unroll
  for (int i = 0; i < 2; ++i)
#pragma unroll
    for (int j = 0; j < 2; ++j) acc[i][j] = (f32x4){0.f, 0.f, 0.f, 0.f};

  auto stage = [&](int b, int k0) {
    GLOAD_LDS(A + aoff + k0, &sA[b][dst]);
    GLOAD_LDS(B + boff + k0, &sB[b][dst]);
  };

  stage(0, 0);
  __syncthreads();
  int buf = 0;
  for (int it = 0; it < 32; ++it) {
    if (it + 1 < 32) stage(buf ^ 1, (it + 1) << 5);
    f16x8 aF[2], bF[2];
#pragma unroll
    for (int mt = 0; mt < 2; ++mt)
      aF[mt] = *(const f16x8*)&sA[buf][(mh + mt * 16) * 32 + frag];
#pragma unroll
    for (int nt = 0; nt < 2; ++nt)
      bF[nt] = *(const f16x8*)&sB[buf][(nh + nt * 16) * 32 + frag];
#pragma unroll
    for (int mt = 0; mt < 2; ++mt)
#pragma unroll
      for (int nt = 0; nt < 2; ++nt)
        acc[mt][nt] = __builtin_amdgcn_mfma_f32_16x16x32_f16(aF[mt], bF[nt], acc[mt][nt], 0, 0, 0);
    __syncthreads();
    buf ^= 1;
  }

#pragma unroll
  for (int mt = 0; mt < 2; ++mt)
#pragma unroll
    for (int nt = 0; nt < 2; ++nt) {
      const f32x4 a = acc[mt][nt];
      const int c = nh + nt * 16 + (lane & 15);
      const float bias = bo[c];
#pragma unroll
      for (int r = 0; r < 4; ++r) {
        const int m = row0 + mh + mt * 16 + ((lane >> 4) << 2) + r;
        const int t = m >> 6, b = m & 63;
        out[((size_t)b * SS + t) * DOUTN + c] = a[r] + bias;
      }
    }
}

// ---------------------------------------------------------------------------
// precompute: merged plain casts (W1 -> W1s, W0 -> B0, x -> xs)
// ---------------------------------------------------------------------------
__global__ __launch_bounds__(256)
void k_cvt_all(const float* __restrict__ W1, const float* __restrict__ W0,
               const float* __restrict__ x,
               f16* __restrict__ W1s, f16* __restrict__ B0, f16* __restrict__ xs) {
  const int i = blockIdx.x * 256 + threadIdx.x;   // float4 index
  const float* src; f16* dst; int j;
  if (i < 262144)      { src = W1; dst = W1s; j = i; }
  else if (i < 524288) { src = W0; dst = B0;  j = i - 262144; }
  else                 { src = x;  dst = xs;  j = i - 524288; }
  const float4 v = ((const float4*)src)[j];
  f16x4 h4;
  h4[0] = (f16)v.x; h4[1] = (f16)v.y; h4[2] = (f16)v.z; h4[3] = (f16)v.w;
  ((f16x4*)dst)[j] = h4;
}

// transpose + cast, two 1024-dim sources via z
__global__ __launch_bounds__(256)
void k_cvtT2(const float* __restrict__ s0, f16* __restrict__ d0,
             const float* __restrict__ s1, f16* __restrict__ d1) {
  const float* src = blockIdx.z ? s1 : s0;
  f16* dst = blockIdx.z ? d1 : d0;
  const int i0 = blockIdx.y * 64, j0 = blockIdx.x * 64;
  __shared__ float tb[64][68];
  const int u = threadIdx.x;
#pragma unroll
  for (int it = 0; it < 4; ++it) {
    const int idx = it * 256 + u, rr = idx >> 4, cc = (idx & 15) * 4;
    *(float4*)&tb[rr][cc] = *(const float4*)&src[(size_t)(i0 + rr) * DD + j0 + cc];
  }
  __syncthreads();
#pragma unroll
  for (int it = 0; it < 4; ++it) {
    const int idx = it * 256 + u, rr = idx >> 4, cc = (idx & 15) * 4;
    f16x4 h4;
#pragma unroll
    for (int j = 0; j < 4; ++j) h4[j] = (f16)tb[cc + j][rr];
    *(f16x4*)&dst[(size_t)(j0 + rr) * DD + i0 + cc] = h4;
  }
}

// transpose + cast for F/G (512-dim, z in [0,6): z<3 -> F slice, else G)
__global__ __launch_bounds__(256)
void k_cvtT_fg(const float* __restrict__ F, const float* __restrict__ G,
               f16* __restrict__ BF, f16* __restrict__ BG) {
  const int z = blockIdx.z;
  const size_t off = (size_t)(z % 3) * 512 * 512;
  const float* src = (z < 3 ? F : G) + off;
  f16* dst = (z < 3 ? BF : BG) + off;
  const int i0 = blockIdx.y * 64, j0 = blockIdx.x * 64;
  __shared__ float tb[64][68];
  const int u = threadIdx.x;
#pragma unroll
  for (int it = 0; it < 4; ++it) {
    const int idx = it * 256 + u, rr = idx >> 4, cc = (idx & 15) * 4;
    *(float4*)&tb[rr][cc] = *(const float4*)&src[(size_t)(i0 + rr) * 512 + j0 + cc];
  }
  __syncthreads();
#pragma unroll
  for (int it = 0; it < 4; ++it) {
    const int idx = it * 256 + u, rr = idx >> 4, cc = (idx & 15) * 4;
    f16x4 h4;
#pragma unroll
    for (int j = 0; j < 4; ++j) h4[j] = (f16)tb[cc + j][rr];
    *(f16x4*)&dst[(size_t)(j0 + rr) * 512 + i0 + cc] = h4;
  }
}

// S = R + R^T, cast f16 (symmetric => [n][k] fine)
__global__ __launch_bounds__(256)
void k_symm_cvt(const float* __restrict__ R, f16* __restrict__ S) {
  const int i0 = blockIdx.y * 64, j0 = blockIdx.x * 64;
  __shared__ float tb[64][68];
  const int u = threadIdx.x;
#pragma unroll
  for (int it = 0; it < 4; ++it) {
    const int idx = it * 256 + u, rr = idx >> 4, cc = (idx & 15) * 4;
    *(float4*)&tb[rr][cc] = *(const float4*)&R[(size_t)(j0 + rr) * DD + i0 + cc];
  }
  __syncthreads();
#pragma unroll
  for (int it = 0; it < 4; ++it) {
    const int idx = it * 256 + u, rr = idx >> 4, cc = (idx & 15) * 4;
    const float4 v = *(const float4*)&R[(size_t)(i0 + rr) * DD + j0 + cc];
    f16x4 h4;
    h4[0] = (f16)(v.x + tb[cc + 0][rr]); h4[1] = (f16)(v.y + tb[cc + 1][rr]);
    h4[2] = (f16)(v.z + tb[cc + 2][rr]); h4[3] = (f16)(v.w + tb[cc + 3][rr]);
    *(f16x4*)&S[(size_t)(i0 + rr) * DD + j0 + cc] = h4;
  }
}

// f16 plane transpose
__global__ __launch_bounds__(256)
void k_tr16(const f16* __restrict__ in, f16* __restrict__ o, int dim) {
  const int i0 = blockIdx.y * 64, j0 = blockIdx.x * 64;
  __shared__ f16 tb[64][72];
  const int u = threadIdx.x;
#pragma unroll
  for (int it = 0; it < 2; ++it) {
    const int C = it * 256 + u, row = C >> 3, ch = C & 7;
    *(f16x8*)&tb[row][ch * 8] = *(const f16x8*)&in[(size_t)(i0 + row) * dim + j0 + ch * 8];
  }
  __syncthreads();
#pragma unroll
  for (int it = 0; it < 2; ++it) {
    const int C = it * 256 + u, row = C >> 3, ch = C & 7;
    f16x8 v;
#pragma unroll
    for (int j = 0; j < 8; ++j) v[j] = tb[ch * 8 + j][row];
    *(f16x8*)&o[(size_t)(j0 + row) * dim + i0 + ch * 8] = v;
  }
}

// A2 = f16(P @ Wi)  ([1024][64])
__global__ __launch_bounds__(256)
void k_pwi(const float* __restrict__ P, const float* __restrict__ Wi,
           f16* __restrict__ A2) {
  const int m0 = blockIdx.x * 4;
  __shared__ float Ps[4][1024];
  const int u = threadIdx.x;
#pragma unroll
  for (int i = 0; i < 4; ++i) {
    const int idx = i * 256 + u, mi = idx >> 8, kc = (idx & 255) * 4;
    *(float4*)&Ps[mi][kc] = *(const float4*)&P[(size_t)(m0 + mi) * DD + kc];
  }
  __syncthreads();
  const int n = u & 63, mi = u >> 6;
  float acc = 0.f;
  for (int k = 0; k < DD; ++k) acc += Ps[mi][k] * Wi[(size_t)k * DINN + n];
  A2[(size_t)(m0 + mi) * DINN + n] = (f16)acc;
}

// MoT [c][d] = f16(sum_k P[d][k] * Wo[c][k])
__global__ __launch_bounds__(256)
void k_pwo(const float* __restrict__ P, const float* __restrict__ Wo_,
           f16* __restrict__ MoT) {
  const int d0 = blockIdx.x * 4;
  __shared__ float Ps[4][1024];
  __shared__ float ws[64][65];
  const int u = threadIdx.x;
#pragma unroll
  for (int i = 0; i < 4; ++i) {
    const int idx = i * 256 + u, mi = idx >> 8, kc = (idx & 255) * 4;
    *(float4*)&Ps[mi][kc] = *(const float4*)&P[(size_t)(d0 + mi) * DD + kc];
  }
  const int c = u & 63, di = u >> 6;
  float acc = 0.f;
  for (int k0 = 0; k0 < DD; k0 += 64) {
    __syncthreads();
#pragma unroll
    for (int i = 0; i < 4; ++i) {
      const int idx = i * 256 + u, cc = idx >> 4, kc = (idx & 15) * 4;
      const float4 v = *(const float4*)&Wo_[(size_t)cc * DD + k0 + kc];
      ws[cc][kc] = v.x; ws[cc][kc + 1] = v.y; ws[cc][kc + 2] = v.z; ws[cc][kc + 3] = v.w;
    }
    __syncthreads();
    for (int kk = 0; kk < 64; ++kk) acc += Ps[di][k0 + kk] * ws[c][kk];
  }
  MoT[(size_t)c * DD + d0 + di] = (f16)acc;
}

// cvec = P @ bi ; wave per row
__global__ __launch_bounds__(256)
void k_matvec(const float* __restrict__ P, const float* __restrict__ b,
              float* __restrict__ c) {
  const int row = blockIdx.x * 4 + (threadIdx.x >> 6);
  const int l = threadIdx.x & 63;
  float s = 0.f;
  for (int k = l; k < DD; k += 64) s += P[(size_t)row * DD + k] * b[k];
  for (int o = 32; o; o >>= 1) s += __shfl_down(s, o, 64);
  if (l == 0) c[row] = s;
}

// ---------------------------------------------------------------------------
extern "C" void kernel_launch(void* const* d_in, const int* in_sizes, int n_in,
                              void* d_out, int out_size, void* d_ws, size_t ws_size,
                              hipStream_t stream) {
  (void)in_sizes; (void)n_in; (void)out_size; (void)ws_size;
  const float* x    = (const float*)d_in[0];
  const float* Wi   = (const float*)d_in[1];
  const float* bi   = (const float*)d_in[2];
  const float* P    = (const float*)d_in[3];
  const float* rotW = (const float*)d_in[4];
  const float* F    = (const float*)d_in[5];
  const float* G    = (const float*)d_in[6];
  const float* R    = (const float*)d_in[7];
  const float* Wo   = (const float*)d_in[8];
  const float* bo   = (const float*)d_in[9];
  float* out = (float*)d_out;
  char* w = (char*)d_ws;

  constexpr size_t MB = 1u << 20;
  // h planes (f16, [8192][1024], single plane)
  f16* haS = (f16*)(w + 0 * MB);       // 16MB
  f16* hbS = (f16*)(w + 16 * MB);      // 16MB
  // weight planes ([n][k] layout), 2MB each
  f16* B0t = (f16*)(w + 32 * MB);      // W0^T
  f16* B12t= (f16*)(w + 34 * MB);      // W12^T
  f16* Bss = (f16*)(w + 36 * MB);      // R+R^T
  f16* B12 = (f16*)(w + 38 * MB);      // W12
  f16* B0  = (f16*)(w + 40 * MB);      // W0
  f16* BF  = (f16*)(w + 42 * MB);      // F^T x3 (1.5MB)
  f16* BG  = (f16*)(w + 44 * MB);      // G^T x3 (1.5MB)
  // small planes / vectors
  f16* MoT    = (f16*)(w + 46 * MB);             // 128KB
  f16* A2     = (f16*)(w + 46 * MB + 128 * 1024);
  float* cvec = (float*)(w + 46 * MB + 256 * 1024);
  f16* xs     = (f16*)(w + 47 * MB);             // 1MB
  // temps
  f16* W1s = (f16*)(w + 48 * MB);      // 2MB
  f16* W2t = (f16*)(w + 50 * MB);      // 2MB
  float* Wp = (float*)(w + 52 * MB);   // 16MB fp32 split-K partials (4 x 4MB)

  const float* W0 = rotW;
  const float* W1 = rotW + (1u << 20);
  const float* W2 = rotW + (2u << 20);

  const dim3 blk256(256);
  const size_t FGQ = (size_t)512 * 512;

  // ---- precompute ----
  k_cvt_all <<<dim3(2560), blk256, 0, stream>>>(W1, W0, x, W1s, B0, xs);
  k_cvtT2   <<<dim3(16, 16, 2), blk256, 0, stream>>>(W2, W2t, W0, B0t);
  k_cvtT_fg <<<dim3(8, 8, 6), blk256, 0, stream>>>(F, G, BF, BG);
  k_symm_cvt<<<dim3(16, 16), blk256, 0, stream>>>(R, Bss);
  // W12 = f16(W1) @ f16(W2), split-K=4 for occupancy
  k_w12part <<<dim3(8, 16, 4), blk256, 0, stream>>>(W1s, W2t, Wp);
  k_sum4    <<<dim3(1024), blk256, 0, stream>>>(Wp, B12);
  k_tr16    <<<dim3(16, 16), blk256, 0, stream>>>(B12, B12t, DD);
  k_pwi     <<<dim3(256), blk256, 0, stream>>>(P, Wi, A2);
  k_pwo     <<<dim3(256), blk256, 0, stream>>>(P, Wo, MoT);
  k_matvec  <<<dim3(256), blk256, 0, stream>>>(P, bi, cvec);

  // ---- main pipeline (single-plane f16, fp32 MFMA accum) ----
  k_in_mfma<<<dim3(8, 128), blk256, 0, stream>>>(xs, A2, cvec, haS);

  // rotor 0 fwd (A pre-rolled, store +t) — BM=64 grid 1024 (4 blocks/CU)
  k_gemm16<64, false, +1><<<dim3(8, 128), blk256, 0, stream>>>(haS, DD, B0t, DD, hbS, DD, DD);
  // rotors 1,2 precomposed
  k_gemm16<64, false, 0><<<dim3(8, 128), blk256, 0, stream>>>(hbS, DD, B12t, DD, haS, DD, DD);
  // reversible blocks fwd (in place on ha; h2 = cols 512.., y1 = cols 0..)
  for (int i = 0; i < 3; ++i) {
    k_gemm16<64, true, 0><<<dim3(4, 128), blk256, 0, stream>>>(haS + 512, DD, BF + i * FGQ, 512, haS, DD, 512);
    k_gemm16<64, true, 0><<<dim3(4, 128), blk256, 0, stream>>>(haS, DD, BG + i * FGQ, 512, haS + 512, DD, 512);
  }
  // reflector
  k_gemm16<64, false, 0><<<dim3(8, 128), blk256, 0, stream>>>(haS, DD, Bss, DD, hbS, DD, DD);
  // reversible blocks reversed (in place on hb)
  for (int i = 2; i >= 0; --i) {
    k_gemm16<64, true, 0><<<dim3(4, 128), blk256, 0, stream>>>(hbS + 512, DD, BF + i * FGQ, 512, hbS, DD, 512);
    k_gemm16<64, true, 0><<<dim3(4, 128), blk256, 0, stream>>>(hbS, DD, BG + i * FGQ, 512, hbS + 512, DD, 512);
  }
  // rotors inverse: W12^T-mult (B = W12 as-is), store pre-rolled (-t)
  k_gemm16<64, false, -1><<<dim3(8, 128), blk256, 0, stream>>>(hbS, DD, B12, DD, haS, DD, DD);
  // rotor 0 inverse: W0^T-mult (B = W0 as-is), store +t -> linear
  k_gemm16<64, false, +1><<<dim3(8, 128), blk256, 0, stream>>>(haS, DD, B0, DD, hbS, DD, DD);

  // output projection
  k_out_mfma<<<dim3(128), blk256, 0, stream>>>(hbS, MoT, bo, out);
}

// Round 16
// 381.869 us; speedup vs baseline: 2.2428x; 1.0509x over previous
//
#include <hip/hip_runtime.h>
#include <math.h>

#define DD 1024
#define MM 8192   // B*S rows
#define SS 128
#define DINN 64
#define DOUTN 64

typedef _Float16 f16;
typedef _Float16 f16x8 __attribute__((ext_vector_type(8)));
typedef _Float16 f16x4 __attribute__((ext_vector_type(4)));
typedef float    f32x4 __attribute__((ext_vector_type(4)));

// direct global->LDS, 16B per lane; LDS base must be wave-uniform
#define GLOAD_LDS(g, l) \
  __builtin_amdgcn_global_load_lds((const __attribute__((address_space(1))) void*)(g), \
                                   (__attribute__((address_space(3))) void*)(l), 16, 0, 0)

// ---------------------------------------------------------------------------
// Single-plane f16 MFMA GEMM (R13-validated numerics).
// A [M][K] f16 (lda), B [N][K] f16 (ldb), C [M][ldc] f16.
// 256 thr / 4 waves; BN=128; BK=32; wave-tile (BM/2)x64; MT=BM/32.
// LDS swizzle s(row)=(row>>1)&3: conflict-free (R7: SQ_LDS_BANK_CONFLICT=0).
// SHIFT: store col = (n + SHIFT*(m>>6)) & 1023 (scalar path).
// EPI:  y = y_old + tanh(y).
// ---------------------------------------------------------------------------
template<int BM, bool EPI, int SHIFT>
__global__ __launch_bounds__(256)
void k_gemm16(const f16* __restrict__ A, int lda,
              const f16* __restrict__ B, int ldb,
              f16* __restrict__ C, int ldc, int K) {
  constexpr int MT = BM / 32;
  constexpr int AI = BM / 64;
  __shared__ f16 sA[2][BM * 32];
  __shared__ f16 sB[2][128 * 32];

  const int nwg = gridDim.x * gridDim.y;
  int wg = blockIdx.y * gridDim.x + blockIdx.x;
  wg = (wg & 7) * (nwg >> 3) + (wg >> 3);
  const int bx = wg % gridDim.x, by = wg / gridDim.x;

  const int col0 = bx * 128, row0 = by * BM;
  const int u = threadIdx.x, lane = u & 63, wv = u >> 6;
  const int mh = (wv >> 1) * (BM >> 1);
  const int nh = (wv & 1) * 64;

  unsigned aoff[AI], boff[2];
  unsigned dstA[AI], dstB[2];
#pragma unroll
  for (int i = 0; i < AI; ++i) {
    const int P = i * 256 + u;
    const int row = P >> 2, kc = (P & 3) ^ ((row >> 1) & 3);
    aoff[i] = (unsigned)(row0 + row) * lda + kc * 8;
    dstA[i] = (i * 256 + wv * 64) * 8;
  }
#pragma unroll
  for (int i = 0; i < 2; ++i) {
    const int P = i * 256 + u;
    const int row = P >> 2, kc = (P & 3) ^ ((row >> 1) & 3);
    boff[i] = (unsigned)(col0 + row) * ldb + kc * 8;
    dstB[i] = (i * 256 + wv * 64) * 8;
  }

  const int frag = (lane & 15) * 32 + (((lane >> 4) ^ ((lane >> 1) & 3)) * 8);

  f32x4 acc[MT][4];
#pragma unroll
  for (int i = 0; i < MT; ++i)
#pragma unroll
    for (int j = 0; j < 4; ++j) acc[i][j] = (f32x4){0.f, 0.f, 0.f, 0.f};

  auto stage = [&](int b, int k0) {
#pragma unroll
    for (int i = 0; i < AI; ++i)
      GLOAD_LDS(A + aoff[i] + k0, &sA[b][dstA[i]]);
#pragma unroll
    for (int i = 0; i < 2; ++i)
      GLOAD_LDS(B + boff[i] + k0, &sB[b][dstB[i]]);
  };

  const int niter = K >> 5;
  stage(0, 0);
  __syncthreads();

  int buf = 0;
  for (int it = 0; it < niter; ++it) {
    if (it + 1 < niter) stage(buf ^ 1, (it + 1) << 5);
    f16x8 aF[MT], bF[4];
#pragma unroll
    for (int mt = 0; mt < MT; ++mt)
      aF[mt] = *(const f16x8*)&sA[buf][(mh + mt * 16) * 32 + frag];
#pragma unroll
    for (int nt = 0; nt < 4; ++nt)
      bF[nt] = *(const f16x8*)&sB[buf][(nh + nt * 16) * 32 + frag];
#pragma unroll
    for (int mt = 0; mt < MT; ++mt)
#pragma unroll
      for (int nt = 0; nt < 4; ++nt)
        acc[mt][nt] = __builtin_amdgcn_mfma_f32_16x16x32_f16(aF[mt], bF[nt], acc[mt][nt], 0, 0, 0);
    __syncthreads();
    buf ^= 1;
  }

  if constexpr (SHIFT == 0) {
    f16* eH = &sB[0][0] + wv * (16 * 84);
    const int lrow4 = (lane >> 4) << 2;
    const int lcol = lane & 15;
#pragma unroll
    for (int mt = 0; mt < MT; ++mt) {
#pragma unroll
      for (int nt = 0; nt < 4; ++nt) {
        const f32x4 a = acc[mt][nt];
#pragma unroll
        for (int r = 0; r < 4; ++r)
          eH[(lrow4 + r) * 84 + nt * 16 + lcol] = (f16)a[r];
      }
#pragma unroll
      for (int j = 0; j < 2; ++j) {
        const int idx = j * 64 + lane;
        const int row = idx >> 3, ch = idx & 7;
        const f16x8 vh = *(const f16x8*)&eH[row * 84 + ch * 8];
        const int m = row0 + mh + mt * 16 + row;
        const size_t gi = (size_t)m * ldc + col0 + nh + ch * 8;
        if (EPI) {
          const f16x8 oh = *(const f16x8*)&C[gi];
          f16x8 rh;
#pragma unroll
          for (int q = 0; q < 8; ++q)
            rh[q] = (f16)((float)oh[q] + tanhf((float)vh[q]));
          *(f16x8*)&C[gi] = rh;
        } else {
          *(f16x8*)&C[gi] = vh;
        }
      }
    }
  } else {
#pragma unroll
    for (int mt = 0; mt < MT; ++mt)
#pragma unroll
      for (int nt = 0; nt < 4; ++nt) {
        const f32x4 a = acc[mt][nt];
        const int n_base = col0 + nh + nt * 16 + (lane & 15);
#pragma unroll
        for (int r = 0; r < 4; ++r) {
          const int m = row0 + mh + mt * 16 + ((lane >> 4) << 2) + r;
          int n = (n_base + SHIFT * (m >> 6) + 2048) & (DD - 1);
          const size_t idx = (size_t)m * ldc + n;
          float y = a[r];
          if (EPI) y = (float)C[idx] + tanhf(y);
          C[idx] = (f16)y;
        }
      }
  }
}

// ---------------------------------------------------------------------------
// W12 AND W12^T split-K partials in one launch.
// z<4: partial of W12   = W1s @ W2t-as-B  (A=W1s, B=W2t), k-slice z*256
// z>=4: partial of W12^T = W2t @ W1s-as-B (A=W2t, B=W1s), k-slice (z-4)*256
// grid (8,16,8); out Wp[z] (fp32 [1024][1024] each).
// ---------------------------------------------------------------------------
__global__ __launch_bounds__(256)
void k_w12both(const f16* __restrict__ W1s, const f16* __restrict__ W2t,
               float* __restrict__ Wp) {
  __shared__ f16 sA[2][64 * 32];
  __shared__ f16 sB[2][128 * 32];
  const int z = blockIdx.z;
  const f16* A = (z < 4) ? W1s : W2t;
  const f16* B = (z < 4) ? W2t : W1s;
  const int kOff = (z & 3) * 256;
  float* Co = Wp + (size_t)z * DD * DD;
  const int col0 = blockIdx.x * 128, row0 = blockIdx.y * 64;
  const int u = threadIdx.x, lane = u & 63, wv = u >> 6;
  const int mh = (wv >> 1) * 32, nh = (wv & 1) * 64;

  unsigned aoff, boff[2], dstA, dstB[2];
  {
    const int row = u >> 2, kc = (u & 3) ^ ((row >> 1) & 3);
    aoff = (unsigned)(row0 + row) * DD + kOff + kc * 8;
    dstA = (unsigned)(wv * 64) * 8;
  }
#pragma unroll
  for (int i = 0; i < 2; ++i) {
    const int P = i * 256 + u;
    const int row = P >> 2, kc = (P & 3) ^ ((row >> 1) & 3);
    boff[i] = (unsigned)(col0 + row) * DD + kOff + kc * 8;
    dstB[i] = (i * 256 + wv * 64) * 8;
  }
  const int frag = (lane & 15) * 32 + (((lane >> 4) ^ ((lane >> 1) & 3)) * 8);

  f32x4 acc[2][4];
#pragma unroll
  for (int i = 0; i < 2; ++i)
#pragma unroll
    for (int j = 0; j < 4; ++j) acc[i][j] = (f32x4){0.f, 0.f, 0.f, 0.f};

  auto stage = [&](int b, int k0) {
    GLOAD_LDS(A + aoff + k0, &sA[b][dstA]);
#pragma unroll
    for (int i = 0; i < 2; ++i)
      GLOAD_LDS(B + boff[i] + k0, &sB[b][dstB[i]]);
  };

  stage(0, 0);
  __syncthreads();
  int buf = 0;
  for (int it = 0; it < 8; ++it) {
    if (it + 1 < 8) stage(buf ^ 1, (it + 1) << 5);
    f16x8 aF[2], bF[4];
#pragma unroll
    for (int mt = 0; mt < 2; ++mt)
      aF[mt] = *(const f16x8*)&sA[buf][(mh + mt * 16) * 32 + frag];
#pragma unroll
    for (int nt = 0; nt < 4; ++nt)
      bF[nt] = *(const f16x8*)&sB[buf][(nh + nt * 16) * 32 + frag];
#pragma unroll
    for (int mt = 0; mt < 2; ++mt)
#pragma unroll
      for (int nt = 0; nt < 4; ++nt)
        acc[mt][nt] = __builtin_amdgcn_mfma_f32_16x16x32_f16(aF[mt], bF[nt], acc[mt][nt], 0, 0, 0);
    __syncthreads();
    buf ^= 1;
  }
#pragma unroll
  for (int mt = 0; mt < 2; ++mt)
#pragma unroll
    for (int nt = 0; nt < 4; ++nt) {
      const f32x4 a = acc[mt][nt];
      const int n = col0 + nh + nt * 16 + (lane & 15);
#pragma unroll
      for (int r = 0; r < 4; ++r) {
        const int m = row0 + mh + mt * 16 + ((lane >> 4) << 2) + r;
        Co[(size_t)m * DD + n] = a[r];
      }
    }
}

// B12 / B12t = f16(sum of 4 fp32 partials each); grid 2048.
__global__ __launch_bounds__(256)
void k_sumboth(const float* __restrict__ Wp, f16* __restrict__ B12,
               f16* __restrict__ B12t) {
  int i = blockIdx.x * 256 + threadIdx.x;   // float4 index over 2x 262144
  const float* base = Wp;
  f16* dst = B12;
  if (i >= 262144) { i -= 262144; base = Wp + (4u << 20); dst = B12t; }
  const float4 s0 = ((const float4*)base)[i];
  const float4 s1 = ((const float4*)(base + (1u << 20)))[i];
  const float4 s2 = ((const float4*)(base + (2u << 20)))[i];
  const float4 s3 = ((const float4*)(base + (3u << 20)))[i];
  f16x4 h4;
  h4[0] = (f16)(s0.x + s1.x + s2.x + s3.x);
  h4[1] = (f16)(s0.y + s1.y + s2.y + s3.y);
  h4[2] = (f16)(s0.z + s1.z + s2.z + s3.z);
  h4[3] = (f16)(s0.w + s1.w + s2.w + s3.w);
  ((f16x4*)dst)[i] = h4;
}

// ---------------------------------------------------------------------------
// input projection as MFMA GEMM (pre-rolled -t via B-row staging)
// ---------------------------------------------------------------------------
__global__ __launch_bounds__(256)
void k_in_mfma(const f16* __restrict__ xS,
               const f16* __restrict__ A2,
               const float* __restrict__ cvec,
               f16* __restrict__ hS) {
  __shared__ f16 sA[2][64 * 32];
  __shared__ f16 sB[2][128 * 32];
  const int bx = blockIdx.x, by = blockIdx.y;
  const int col0 = bx * 128, row0 = by * 64, t = by;
  const int u = threadIdx.x, lane = u & 63, wv = u >> 6;
  const int mh = (wv >> 1) * 32;
  const int nh = (wv & 1) * 64;

  unsigned aoff, boff[2], dstA, dstB[2];
  {
    const int row = u >> 2, kc = (u & 3) ^ ((row >> 1) & 3);
    aoff = (unsigned)(row * SS + t) * DINN + kc * 8;
    dstA = (unsigned)(wv * 64) * 8;
  }
#pragma unroll
  for (int i = 0; i < 2; ++i) {
    const int P = i * 256 + u;
    const int row = P >> 2, kc = (P & 3) ^ ((row >> 1) & 3);
    const int src = (col0 + row + t) & (DD - 1);
    boff[i] = (unsigned)src * DINN + kc * 8;
    dstB[i] = (i * 256 + wv * 64) * 8;
  }

  const int frag = (lane & 15) * 32 + (((lane >> 4) ^ ((lane >> 1) & 3)) * 8);

  f32x4 acc[2][4];
#pragma unroll
  for (int i = 0; i < 2; ++i)
#pragma unroll
    for (int j = 0; j < 4; ++j) acc[i][j] = (f32x4){0.f, 0.f, 0.f, 0.f};

  auto stage = [&](int b, int k0) {
    GLOAD_LDS(xS + aoff + k0, &sA[b][dstA]);
#pragma unroll
    for (int i = 0; i < 2; ++i)
      GLOAD_LDS(A2 + boff[i] + k0, &sB[b][dstB[i]]);
  };

  stage(0, 0);
  __syncthreads();
  int buf = 0;
#pragma unroll
  for (int it = 0; it < 2; ++it) {
    if (it == 0) stage(1, 32);
    f16x8 aF[2], bF[4];
#pragma unroll
    for (int mt = 0; mt < 2; ++mt)
      aF[mt] = *(const f16x8*)&sA[buf][(mh + mt * 16) * 32 + frag];
#pragma unroll
    for (int nt = 0; nt < 4; ++nt)
      bF[nt] = *(const f16x8*)&sB[buf][(nh + nt * 16) * 32 + frag];
#pragma unroll
    for (int mt = 0; mt < 2; ++mt)
#pragma unroll
      for (int nt = 0; nt < 4; ++nt)
        acc[mt][nt] = __builtin_amdgcn_mfma_f32_16x16x32_f16(aF[mt], bF[nt], acc[mt][nt], 0, 0, 0);
    __syncthreads();
    buf ^= 1;
  }

  f16* eH = &sB[0][0] + wv * (16 * 84);
  const int lrow4 = (lane >> 4) << 2;
  const int lcol = lane & 15;
#pragma unroll
  for (int mt = 0; mt < 2; ++mt) {
#pragma unroll
    for (int nt = 0; nt < 4; ++nt) {
      const f32x4 a = acc[mt][nt];
      const int n = col0 + nh + nt * 16 + lcol;
      const float cv = cvec[(n + t) & (DD - 1)];
#pragma unroll
      for (int r = 0; r < 4; ++r)
        eH[(lrow4 + r) * 84 + nt * 16 + lcol] = (f16)(a[r] + cv);
    }
#pragma unroll
    for (int j = 0; j < 2; ++j) {
      const int idx = j * 64 + lane;
      const int row = idx >> 3, ch = idx & 7;
      const f16x8 vh = *(const f16x8*)&eH[row * 84 + ch * 8];
      const int m = row0 + mh + mt * 16 + row;
      *(f16x8*)&hS[(size_t)m * DD + col0 + nh + ch * 8] = vh;
    }
  }
}

// ---------------------------------------------------------------------------
// output projection as MFMA GEMM: out[b][t][c] = (h @ MoT^T)[r][c] + bo[c]
// ---------------------------------------------------------------------------
__global__ __launch_bounds__(256)
void k_out_mfma(const f16* __restrict__ A,
                const f16* __restrict__ B,
                const float* __restrict__ bo, float* __restrict__ out) {
  __shared__ f16 sA[2][64 * 32];
  __shared__ f16 sB[2][64 * 32];
  const int row0 = blockIdx.x * 64;
  const int u = threadIdx.x, lane = u & 63, wv = u >> 6;
  const int mh = (wv >> 1) * 32, nh = (wv & 1) * 32;

  const int srow = u >> 2, skc = (u & 3) ^ ((srow >> 1) & 3);
  const unsigned aoff = (unsigned)(row0 + srow) * DD + skc * 8;
  const unsigned boff = (unsigned)srow * DD + skc * 8;
  const unsigned dst = (unsigned)(wv * 64) * 8;

  const int frag = (lane & 15) * 32 + (((lane >> 4) ^ ((lane >> 1) & 3)) * 8);

  f32x4 acc[2][2];
#pragma unroll
  for (int i = 0; i < 2; ++i)
#pragma unroll
    for (int j = 0; j < 2; ++j) acc[i][j] = (f32x4){0.f, 0.f, 0.f, 0.f};

  auto stage = [&](int b, int k0) {
    GLOAD_LDS(A + aoff + k0, &sA[b][dst]);
    GLOAD_LDS(B + boff + k0, &sB[b][dst]);
  };

  stage(0, 0);
  __syncthreads();
  int buf = 0;
  for (int it = 0; it < 32; ++it) {
    if (it + 1 < 32) stage(buf ^ 1, (it + 1) << 5);
    f16x8 aF[2], bF[2];
#pragma unroll
    for (int mt = 0; mt < 2; ++mt)
      aF[mt] = *(const f16x8*)&sA[buf][(mh + mt * 16) * 32 + frag];
#pragma unroll
    for (int nt = 0; nt < 2; ++nt)
      bF[nt] = *(const f16x8*)&sB[buf][(nh + nt * 16) * 32 + frag];
#pragma unroll
    for (int mt = 0; mt < 2; ++mt)
#pragma unroll
      for (int nt = 0; nt < 2; ++nt)
        acc[mt][nt] = __builtin_amdgcn_mfma_f32_16x16x32_f16(aF[mt], bF[nt], acc[mt][nt], 0, 0, 0);
    __syncthreads();
    buf ^= 1;
  }

#pragma unroll
  for (int mt = 0; mt < 2; ++mt)
#pragma unroll
    for (int nt = 0; nt < 2; ++nt) {
      const f32x4 a = acc[mt][nt];
      const int c = nh + nt * 16 + (lane & 15);
      const float bias = bo[c];
#pragma unroll
      for (int r = 0; r < 4; ++r) {
        const int m = row0 + mh + mt * 16 + ((lane >> 4) << 2) + r;
        const int t = m >> 6, b = m & 63;
        out[((size_t)b * SS + t) * DOUTN + c] = a[r] + bias;
      }
    }
}

// ---------------------------------------------------------------------------
// precompute: merged plain casts (W1 -> W1s, W0 -> B0, x -> xs)
// ---------------------------------------------------------------------------
__global__ __launch_bounds__(256)
void k_cvt_all(const float* __restrict__ W1, const float* __restrict__ W0,
               const float* __restrict__ x,
               f16* __restrict__ W1s, f16* __restrict__ B0, f16* __restrict__ xs) {
  const int i = blockIdx.x * 256 + threadIdx.x;
  const float* src; f16* dst; int j;
  if (i < 262144)      { src = W1; dst = W1s; j = i; }
  else if (i < 524288) { src = W0; dst = B0;  j = i - 262144; }
  else                 { src = x;  dst = xs;  j = i - 524288; }
  const float4 v = ((const float4*)src)[j];
  f16x4 h4;
  h4[0] = (f16)v.x; h4[1] = (f16)v.y; h4[2] = (f16)v.z; h4[3] = (f16)v.w;
  ((f16x4*)dst)[j] = h4;
}

// all transpose+casts, z-muxed: z=0 W2->W2t, z=1 W0->B0t, z=2..4 F, z=5..7 G
__global__ __launch_bounds__(256)
void k_cvtT_all(const float* __restrict__ W2, const float* __restrict__ W0,
                const float* __restrict__ F, const float* __restrict__ G,
                f16* __restrict__ W2t, f16* __restrict__ B0t,
                f16* __restrict__ BF, f16* __restrict__ BG) {
  const int z = blockIdx.z;
  const float* src; f16* dst; int dim;
  if (z == 0)      { src = W2; dst = W2t; dim = DD; }
  else if (z == 1) { src = W0; dst = B0t; dim = DD; }
  else {
    const int idx = z - 2;
    const size_t off = (size_t)(idx % 3) * 512 * 512;
    src = (idx < 3 ? F : G) + off;
    dst = (idx < 3 ? BF : BG) + off;
    dim = 512;
    if (blockIdx.x >= 8 || blockIdx.y >= 8) return;
  }
  const int i0 = blockIdx.y * 64, j0 = blockIdx.x * 64;
  __shared__ float tb[64][68];
  const int u = threadIdx.x;
#pragma unroll
  for (int it = 0; it < 4; ++it) {
    const int idx = it * 256 + u, rr = idx >> 4, cc = (idx & 15) * 4;
    *(float4*)&tb[rr][cc] = *(const float4*)&src[(size_t)(i0 + rr) * dim + j0 + cc];
  }
  __syncthreads();
#pragma unroll
  for (int it = 0; it < 4; ++it) {
    const int idx = it * 256 + u, rr = idx >> 4, cc = (idx & 15) * 4;
    f16x4 h4;
#pragma unroll
    for (int j = 0; j < 4; ++j) h4[j] = (f16)tb[cc + j][rr];
    *(f16x4*)&dst[(size_t)(j0 + rr) * dim + i0 + cc] = h4;
  }
}

// S = R + R^T, cast f16 (symmetric => [n][k] fine)
__global__ __launch_bounds__(256)
void k_symm_cvt(const float* __restrict__ R, f16* __restrict__ S) {
  const int i0 = blockIdx.y * 64, j0 = blockIdx.x * 64;
  __shared__ float tb[64][68];
  const int u = threadIdx.x;
#pragma unroll
  for (int it = 0; it < 4; ++it) {
    const int idx = it * 256 + u, rr = idx >> 4, cc = (idx & 15) * 4;
    *(float4*)&tb[rr][cc] = *(const float4*)&R[(size_t)(j0 + rr) * DD + i0 + cc];
  }
  __syncthreads();
#pragma unroll
  for (int it = 0; it < 4; ++it) {
    const int idx = it * 256 + u, rr = idx >> 4, cc = (idx & 15) * 4;
    const float4 v = *(const float4*)&R[(size_t)(i0 + rr) * DD + j0 + cc];
    f16x4 h4;
    h4[0] = (f16)(v.x + tb[cc + 0][rr]); h4[1] = (f16)(v.y + tb[cc + 1][rr]);
    h4[2] = (f16)(v.z + tb[cc + 2][rr]); h4[3] = (f16)(v.w + tb[cc + 3][rr]);
    *(f16x4*)&S[(size_t)(i0 + rr) * DD + j0 + cc] = h4;
  }
}

// merged small precompute: blocks 0..255 pwi, 256..511 pwo, 512..767 matvec
__global__ __launch_bounds__(256)
void k_small(const float* __restrict__ P, const float* __restrict__ Wi,
             const float* __restrict__ Wo_, const float* __restrict__ bi,
             f16* __restrict__ A2, f16* __restrict__ MoT,
             float* __restrict__ cvec) {
  __shared__ float Ps[4][1024];
  __shared__ float ws[64][65];
  const int u = threadIdx.x;
  const int bb = blockIdx.x;
  if (bb < 256) {
    // A2 = f16(P @ Wi)
    const int m0 = bb * 4;
#pragma unroll
    for (int i = 0; i < 4; ++i) {
      const int idx = i * 256 + u, mi = idx >> 8, kc = (idx & 255) * 4;
      *(float4*)&Ps[mi][kc] = *(const float4*)&P[(size_t)(m0 + mi) * DD + kc];
    }
    __syncthreads();
    const int n = u & 63, mi = u >> 6;
    float acc = 0.f;
    for (int k = 0; k < DD; ++k) acc += Ps[mi][k] * Wi[(size_t)k * DINN + n];
    A2[(size_t)(m0 + mi) * DINN + n] = (f16)acc;
  } else if (bb < 512) {
    // MoT[c][d] = f16(sum_k P[d][k] Wo[c][k])
    const int d0 = (bb - 256) * 4;
#pragma unroll
    for (int i = 0; i < 4; ++i) {
      const int idx = i * 256 + u, mi = idx >> 8, kc = (idx & 255) * 4;
      *(float4*)&Ps[mi][kc] = *(const float4*)&P[(size_t)(d0 + mi) * DD + kc];
    }
    const int c = u & 63, di = u >> 6;
    float acc = 0.f;
    for (int k0 = 0; k0 < DD; k0 += 64) {
      __syncthreads();
#pragma unroll
      for (int i = 0; i < 4; ++i) {
        const int idx = i * 256 + u, cc = idx >> 4, kc = (idx & 15) * 4;
        const float4 v = *(const float4*)&Wo_[(size_t)cc * DD + k0 + kc];
        ws[cc][kc] = v.x; ws[cc][kc + 1] = v.y; ws[cc][kc + 2] = v.z; ws[cc][kc + 3] = v.w;
      }
      __syncthreads();
      for (int kk = 0; kk < 64; ++kk) acc += Ps[di][k0 + kk] * ws[c][kk];
    }
    MoT[(size_t)c * DD + d0 + di] = (f16)acc;
  } else {
    // cvec = P @ bi ; wave per row
    const int row = (bb - 512) * 4 + (u >> 6);
    const int l = u & 63;
    float s = 0.f;
    for (int k = l; k < DD; k += 64) s += P[(size_t)row * DD + k] * bi[k];
    for (int o = 32; o; o >>= 1) s += __shfl_down(s, o, 64);
    if (l == 0) cvec[row] = s;
  }
}

// ---------------------------------------------------------------------------
extern "C" void kernel_launch(void* const* d_in, const int* in_sizes, int n_in,
                              void* d_out, int out_size, void* d_ws, size_t ws_size,
                              hipStream_t stream) {
  (void)in_sizes; (void)n_in; (void)out_size; (void)ws_size;
  const float* x    = (const float*)d_in[0];
  const float* Wi   = (const float*)d_in[1];
  const float* bi   = (const float*)d_in[2];
  const float* P    = (const float*)d_in[3];
  const float* rotW = (const float*)d_in[4];
  const float* F    = (const float*)d_in[5];
  const float* G    = (const float*)d_in[6];
  const float* R    = (const float*)d_in[7];
  const float* Wo   = (const float*)d_in[8];
  const float* bo   = (const float*)d_in[9];
  float* out = (float*)d_out;
  char* w = (char*)d_ws;

  constexpr size_t MB = 1u << 20;
  f16* haS = (f16*)(w + 0 * MB);       // 16MB
  f16* hbS = (f16*)(w + 16 * MB);      // 16MB
  f16* B0t = (f16*)(w + 32 * MB);
  f16* B12t= (f16*)(w + 34 * MB);
  f16* Bss = (f16*)(w + 36 * MB);
  f16* B12 = (f16*)(w + 38 * MB);
  f16* B0  = (f16*)(w + 40 * MB);
  f16* BF  = (f16*)(w + 42 * MB);
  f16* BG  = (f16*)(w + 44 * MB);
  f16* MoT    = (f16*)(w + 46 * MB);
  f16* A2     = (f16*)(w + 46 * MB + 128 * 1024);
  float* cvec = (float*)(w + 46 * MB + 256 * 1024);
  f16* xs     = (f16*)(w + 47 * MB);
  f16* W1s = (f16*)(w + 48 * MB);
  f16* W2t = (f16*)(w + 50 * MB);
  float* Wp = (float*)(w + 52 * MB);   // 32MB fp32 split-K partials (8 x 4MB)

  const float* W0 = rotW;
  const float* W1 = rotW + (1u << 20);
  const float* W2 = rotW + (2u << 20);

  const dim3 blk256(256);
  const size_t FGQ = (size_t)512 * 512;

  // ---- precompute ----
  k_cvt_all <<<dim3(2560), blk256, 0, stream>>>(W1, W0, x, W1s, B0, xs);
  k_cvtT_all<<<dim3(16, 16, 8), blk256, 0, stream>>>(W2, W0, F, G, W2t, B0t, BF, BG);
  k_symm_cvt<<<dim3(16, 16), blk256, 0, stream>>>(R, Bss);
  k_w12both <<<dim3(8, 16, 8), blk256, 0, stream>>>(W1s, W2t, Wp);
  k_sumboth <<<dim3(2048), blk256, 0, stream>>>(Wp, B12, B12t);
  k_small   <<<dim3(768), blk256, 0, stream>>>(P, Wi, Wo, bi, A2, MoT, cvec);

  // ---- main pipeline (single-plane f16, fp32 MFMA accum) ----
  k_in_mfma<<<dim3(8, 128), blk256, 0, stream>>>(xs, A2, cvec, haS);

  // rotor 0 fwd (A pre-rolled, store +t)
  k_gemm16<64, false, +1><<<dim3(8, 128), blk256, 0, stream>>>(haS, DD, B0t, DD, hbS, DD, DD);
  // rotors 1,2 precomposed
  k_gemm16<64, false, 0><<<dim3(8, 128), blk256, 0, stream>>>(hbS, DD, B12t, DD, haS, DD, DD);
  // reversible blocks fwd (in place on ha)
  for (int i = 0; i < 3; ++i) {
    k_gemm16<64, true, 0><<<dim3(4, 128), blk256, 0, stream>>>(haS + 512, DD, BF + i * FGQ, 512, haS, DD, 512);
    k_gemm16<64, true, 0><<<dim3(4, 128), blk256, 0, stream>>>(haS, DD, BG + i * FGQ, 512, haS + 512, DD, 512);
  }
  // reflector
  k_gemm16<64, false, 0><<<dim3(8, 128), blk256, 0, stream>>>(haS, DD, Bss, DD, hbS, DD, DD);
  // reversible blocks reversed (in place on hb)
  for (int i = 2; i >= 0; --i) {
    k_gemm16<64, true, 0><<<dim3(4, 128), blk256, 0, stream>>>(hbS + 512, DD, BF + i * FGQ, 512, hbS, DD, 512);
    k_gemm16<64, true, 0><<<dim3(4, 128), blk256, 0, stream>>>(hbS, DD, BG + i * FGQ, 512, hbS + 512, DD, 512);
  }
  // rotors inverse: W12^T-mult (B = W12 as-is), store pre-rolled (-t)
  k_gemm16<64, false, -1><<<dim3(8, 128), blk256, 0, stream>>>(hbS, DD, B12, DD, haS, DD, DD);
  // rotor 0 inverse: W0^T-mult (B = W0 as-is), store +t -> linear
  k_gemm16<64, false, +1><<<dim3(8, 128), blk256, 0, stream>>>(haS, DD, B0, DD, hbS, DD, DD);

  // output projection
  k_out_mfma<<<dim3(128), blk256, 0, stream>>>(hbS, MoT, bo, out);
}